// Round 11
// baseline (2027.751 us; speedup 1.0000x reference)
//
#include <hip/hip_runtime.h>
#include <hip/hip_fp16.h>

#define N_NODES 500000
#define N_EDGES 1000000
#define N_GRAPHS 20000

typedef _Float16 f16x8 __attribute__((ext_vector_type(8)));
typedef float f32x4 __attribute__((ext_vector_type(4)));

__global__ __launch_bounds__(256) void fill_u32(unsigned* p, unsigned v, int n) {
  int i = blockIdx.x * 256 + threadIdx.x;
  if (i < n) p[i] = v;
}

__global__ __launch_bounds__(256) void hist_dst(const int* __restrict__ dst, int* cnt, int e) {
  int i = blockIdx.x * 256 + threadIdx.x;
  if (i < e) atomicAdd(&cnt[dst[i]], 1);
}

// ---- 2-level exclusive scan over deg[N] (1024 elems/block) ----
__global__ __launch_bounds__(256) void scanA(const int* __restrict__ deg, int* __restrict__ loc,
                                             int* __restrict__ partials, int n) {
  __shared__ int ts[256];
  int b = blockIdx.x, t = threadIdx.x;
  int base = b * 1024 + t * 4;
  int v[4], s = 0;
#pragma unroll
  for (int j = 0; j < 4; ++j) {
    v[j] = (base + j < n) ? deg[base + j] : 0;
    s += v[j];
  }
  ts[t] = s;
  __syncthreads();
  for (int off = 1; off < 256; off <<= 1) {
    int x = (t >= off) ? ts[t - off] : 0;
    __syncthreads();
    ts[t] += x;
    __syncthreads();
  }
  if (t == 255) partials[b] = ts[255];
  int run = ts[t] - s;  // exclusive
#pragma unroll
  for (int j = 0; j < 4; ++j) {
    if (base + j < n) loc[base + j] = run;
    run += v[j];
  }
}

__global__ __launch_bounds__(512) void scanB(int* partials, int nb) {
  __shared__ int s[512];
  int t = threadIdx.x;
  s[t] = (t < nb) ? partials[t] : 0;
  __syncthreads();
  if (t == 0) {
    int run = 0;
    for (int i = 0; i < nb; ++i) { int v = s[i]; s[i] = run; run += v; }
  }
  __syncthreads();
  if (t < nb) partials[t] = s[t];
}

__global__ __launch_bounds__(256) void scanC(int* __restrict__ rowptr, const int* __restrict__ partials,
                                             int* __restrict__ cur, int n, int e) {
  int i = blockIdx.x * 256 + threadIdx.x;
  if (i < n) {
    int v = rowptr[i] + partials[i >> 10];
    rowptr[i] = v;
    cur[i] = v;
  }
  if (i == 0) rowptr[n] = e;
}

__global__ __launch_bounds__(256) void dinv_k(const int* __restrict__ rowptr, float* dinv, int n) {
  int i = blockIdx.x * 256 + threadIdx.x;
  if (i < n) dinv[i] = rsqrtf(1.0f + (float)(rowptr[i + 1] - rowptr[i]));
}

__global__ __launch_bounds__(256) void bucket(const int* __restrict__ src, const int* __restrict__ dst,
                                              int* __restrict__ cur, int* __restrict__ ssrc, int e) {
  int i = blockIdx.x * 256 + threadIdx.x;
  if (i < e) ssrc[atomicAdd(&cur[dst[i]], 1)] = src[i];
}

// ell[n] = {deg, s0, s1, s2} (first 3 srcs inline; overflow stays in CSR)
__global__ __launch_bounds__(256) void ell_build(const int* __restrict__ rowptr,
                                                 const int* __restrict__ ssrc,
                                                 int4* __restrict__ ell, int n) {
  int i = blockIdx.x * 256 + threadIdx.x;
  if (i >= n) return;
  int r0 = rowptr[i], r1 = rowptr[i + 1];
  int deg = r1 - r0;
  int4 e;
  e.x = deg;
  e.y = (deg > 0) ? ssrc[r0] : 0;
  e.z = (deg > 1) ? ssrc[r0 + 1] : 0;
  e.w = (deg > 2) ? ssrc[r0 + 2] : 0;
  ell[i] = e;
}

// gstart[g] = first node index of graph g (batch sorted); gstart[G] = N
__global__ __launch_bounds__(256) void graph_starts(const int* __restrict__ batch,
                                                    int* __restrict__ gstart, int n) {
  int i = blockIdx.x * 256 + threadIdx.x;
  if (i < n) {
    int b = batch[i];
    int bp = (i == 0) ? -1 : batch[i - 1];
    for (int g = bp + 1; g <= b; ++g) gstart[g] = i;
  } else if (i == n) {
    int bl = batch[n - 1];
    for (int g = bl + 1; g <= N_GRAPHS; ++g) gstart[g] = n;
  }
}

// WT[c][k'] = f16(W[k][c]); CHUNK96: k'=(96-blk) layout, valid (k'%96)<78, k=78*(k'/96)+k'%96
template <int CHUNK96>
__global__ __launch_bounds__(256) void wt_conv(const float* __restrict__ W, _Float16* __restrict__ WT,
                                               int K, int Nout, int ldw, int KP, int total) {
  int i = blockIdx.x * 256 + threadIdx.x;
  if (i >= total) return;
  int c = i / KP, kp = i - c * KP;
  int k; bool valid;
  if (CHUNK96) { int blk = kp / 96, r = kp - blk * 96; k = blk * 78 + r; valid = (r < 78) && (k < K); }
  else { k = kp; valid = kp < K; }
  WT[i] = (valid && c < Nout) ? (_Float16)W[(size_t)k * ldw + c] : (_Float16)0.f;
}

// Xh[n, 0:96] = f16(x[n, 0:78]), zero pad
__global__ __launch_bounds__(256) void xconv(const float* __restrict__ x, _Float16* __restrict__ Xh) {
  unsigned idx = blockIdx.x * 256u + threadIdx.x;
  if (idx >= (unsigned)N_NODES * 48u) return;
  unsigned n = idx / 48u, c2 = idx - n * 48u;
  __half2 h = __floats2half2_rn(0.f, 0.f);
  if (c2 < 39u) {
    float2 v = *reinterpret_cast<const float2*>(x + (size_t)n * 78 + 2 * c2);
    h = __floats2half2_rn(v.x, v.y);
  }
  *reinterpret_cast<__half2*>((__half*)Xh + (size_t)n * 96 + 2 * c2) = h;
}

// Direct-register MFMA GEMM. in [M,KP] f16 zero-padded; WT [*,KP] f16 pre-transposed.
// Tile 128x80, 4 waves.
// BLDS=1: stage B once in LDS in fragment-linear order (conflict-free ds_read_b128),
// single barrier, no in-loop barriers.
// PLANE=1: blockIdx.x selects an output plane (out16 += x*planeStride, WT += x*78*KP).
// OUT_MODE 0: v*rs[row] -> f16 ; 1: relu(v+bo) -> f16 ; 2: v+bo -> f32
template <int KP, int OUT_MODE, int BLDS, int PLANE>
__global__ __launch_bounds__(256) void gemm_direct(
    const _Float16* __restrict__ in, const _Float16* __restrict__ WT,
    void* __restrict__ outp, const float* __restrict__ rs, const float* __restrict__ bo,
    int M, int Nout, int LDO, size_t planeStride) {
  constexpr int NS = KP / 32;
  __shared__ _Float16 Bs[BLDS ? 5 * NS * 64 * 8 : 8];
  const int tid = threadIdx.x;
  const int lane = tid & 63;
  const int wid = tid >> 6;
  const int row0 = blockIdx.y * 128;
  const int col0 = PLANE ? 0 : blockIdx.x * 80;
  const _Float16* wt = WT + (size_t)(PLANE ? blockIdx.x * 78 : col0) * KP;
  _Float16* out16 = (_Float16*)outp + (PLANE ? (size_t)blockIdx.x * planeStride : 0);
  float* out32 = (float*)outp;
  const int koff = (lane >> 4) * 8;
  const int gr0 = row0 + wid * 32 + (lane & 15);
  const bool v0 = gr0 < M, v1 = (gr0 + 16) < M;
  const _Float16* a0 = in + (size_t)gr0 * KP + koff;
  const _Float16* a1 = a0 + (size_t)16 * KP;
  const _Float16* bp = wt + (size_t)(lane & 15) * KP + koff;

  if (BLDS) {
    // frag i -> lane i&63, nf (i>>6)%5, step i/320 ; B row = nf*16 + (l&15)
    for (int i = tid; i < 5 * NS * 64; i += 256) {
      int l = i & 63;
      int nf = (i >> 6) % 5;
      int s = i / 320;
      int r = nf * 16 + (l & 15);
      int k = s * 32 + ((l >> 4) << 3);
      *reinterpret_cast<uint4*>(&Bs[(size_t)i * 8]) =
          *reinterpret_cast<const uint4*>(wt + (size_t)r * KP + k);
    }
    __syncthreads();
  }

  const f16x8 zf = {0, 0, 0, 0, 0, 0, 0, 0};
  const f32x4 z4 = {0.f, 0.f, 0.f, 0.f};
  f32x4 acc[2][5];
#pragma unroll
  for (int a = 0; a < 2; ++a)
#pragma unroll
    for (int b = 0; b < 5; ++b) acc[a][b] = z4;

#pragma unroll
  for (int s = 0; s < NS; ++s) {
    f16x8 af0 = v0 ? *reinterpret_cast<const f16x8*>(a0 + s * 32) : zf;
    f16x8 af1 = v1 ? *reinterpret_cast<const f16x8*>(a1 + s * 32) : zf;
    f16x8 bf[5];
#pragma unroll
    for (int nf = 0; nf < 5; ++nf) {
      if (BLDS)
        bf[nf] = *reinterpret_cast<const f16x8*>(&Bs[((size_t)(s * 5 + nf) * 64 + lane) * 8]);
      else
        bf[nf] = *reinterpret_cast<const f16x8*>(bp + (size_t)nf * 16 * KP + s * 32);
    }
#pragma unroll
    for (int nf = 0; nf < 5; ++nf) {
      acc[0][nf] = __builtin_amdgcn_mfma_f32_16x16x32_f16(af0, bf[nf], acc[0][nf], 0, 0, 0);
      acc[1][nf] = __builtin_amdgcn_mfma_f32_16x16x32_f16(af1, bf[nf], acc[1][nf], 0, 0, 0);
    }
  }

  // epilogue: C/D col=lane&15, row=(lane>>4)*4+reg
#pragma unroll
  for (int rf = 0; rf < 2; ++rf) {
#pragma unroll
    for (int j = 0; j < 4; ++j) {
      int gr = row0 + wid * 32 + rf * 16 + (lane >> 4) * 4 + j;
      if (gr >= M) continue;
      float sc = (OUT_MODE == 0) ? rs[gr] : 0.f;
#pragma unroll
      for (int nf = 0; nf < 5; ++nf) {
        int oc = col0 + nf * 16 + (lane & 15);
        if (oc >= Nout) continue;
        float v = acc[rf][nf][j];
        if (OUT_MODE == 0) {
          out16[(size_t)gr * LDO + oc] = (_Float16)(v * sc);
        } else if (OUT_MODE == 1) {
          out16[(size_t)gr * LDO + oc] = (_Float16)fmaxf(v + bo[oc], 0.f);
        } else {
          out32[(size_t)gr * LDO + oc] = v + bo[oc];
        }
      }
    }
  }
}

__device__ inline void acc8(float* a, uint4 v) {
  const __half2* h = reinterpret_cast<const __half2*>(&v);
#pragma unroll
  for (int j = 0; j < 4; ++j) {
    float2 f = __half22float2(h[j]);
    a[2 * j] += f.x;
    a[2 * j + 1] += f.y;
  }
}

__device__ inline void gather_sum(float* a, const _Float16* hbase, unsigned n,
                                  const int4* __restrict__ ell,
                                  const int* __restrict__ rowptr,
                                  const int* __restrict__ ssrc) {
  int4 e = ell[n];
  const int deg = e.x;
  uint4 sv = *reinterpret_cast<const uint4*>(hbase + (size_t)n * 80);
  uint4 g0, g1, g2;
  if (deg > 0) g0 = *reinterpret_cast<const uint4*>(hbase + (size_t)e.y * 80);
  if (deg > 1) g1 = *reinterpret_cast<const uint4*>(hbase + (size_t)e.z * 80);
  if (deg > 2) g2 = *reinterpret_cast<const uint4*>(hbase + (size_t)e.w * 80);
  {
    const __half2* h = reinterpret_cast<const __half2*>(&sv);
#pragma unroll
    for (int j = 0; j < 4; ++j) {
      float2 f = __half22float2(h[j]);
      a[2 * j] = f.x;
      a[2 * j + 1] = f.y;
    }
  }
  if (deg > 0) acc8(a, g0);
  if (deg > 1) acc8(a, g1);
  if (deg > 2) acc8(a, g2);
  if (deg > 3) {
    int r = rowptr[n] + 3, r1 = r + deg - 3;
    for (; r + 2 <= r1; r += 2) {
      uint4 va = *reinterpret_cast<const uint4*>(hbase + (size_t)ssrc[r] * 80);
      uint4 vb = *reinterpret_cast<const uint4*>(hbase + (size_t)ssrc[r + 1] * 80);
      acc8(a, va);
      acc8(a, vb);
    }
    if (r < r1) {
      uint4 va = *reinterpret_cast<const uint4*>(hbase + (size_t)ssrc[r] * 80);
      acc8(a, va);
    }
  }
}

// Fused segment-sum + transform, 16B per thread (10 threads/node, hs stride 80).
// dsth[n, wcoff + q*8 + j] = f16(relu(dinv[n]*(hs[n]+Σ hs[src]) + b[boff+q*8+j]))
__global__ __launch_bounds__(256) void aggregate16B(
    const _Float16* __restrict__ hs, const int4* __restrict__ ell,
    const int* __restrict__ rowptr, const int* __restrict__ ssrc,
    const float* __restrict__ dinv, const float* __restrict__ b,
    _Float16* __restrict__ dsth, int ldo, int boff, int wcoff) {
  unsigned idx = blockIdx.x * 256u + threadIdx.x;
  if (idx >= (unsigned)N_NODES * 10u) return;
  unsigned n = idx / 10u, q = idx - n * 10u;
  float a[8];
  gather_sum(a, hs + 8u * q, n, ell, rowptr, ssrc);
  float di = dinv[n];
  _Float16 ov[8];
#pragma unroll
  for (int j = 0; j < 8; ++j) {
    int col = q * 8 + j;
    float bv = (col < 78) ? b[boff + col] : 0.f;
    ov[j] = (_Float16)fmaxf(fmaf(di, a[j], bv), 0.f);
  }
  *reinterpret_cast<uint4*>(dsth + (size_t)n * ldo + wcoff + q * 8) =
      *reinterpret_cast<const uint4*>(ov);
}

// Layer-3 fused aggregate + graph-pool. Computes relu'd node values in f32 and
// accumulates them per-graph: LDS part[8][80] by local graph index (batch sorted,
// a block's ~26 nodes span few graphs), flushed with one atomicAdd per nonzero
// cell into gsum[G,320] (f32, L2-resident). Overflow (rel>=8) -> direct atomics.
__global__ __launch_bounds__(256) void agg_pool(
    const _Float16* __restrict__ hs, const int4* __restrict__ ell,
    const int* __restrict__ rowptr, const int* __restrict__ ssrc,
    const float* __restrict__ dinv, const float* __restrict__ b, int boff,
    const int* __restrict__ batch, float* __restrict__ gsum, int coff) {
  __shared__ float part[8][80];
  __shared__ int sgbase;
  const int tid = threadIdx.x;
  unsigned idx = blockIdx.x * 256u + tid;
  for (int i = tid; i < 640; i += 256) (&part[0][0])[i] = 0.f;
  if (tid == 0) sgbase = batch[(blockIdx.x * 256u) / 10u];
  __syncthreads();

  const bool active = idx < (unsigned)N_NODES * 10u;
  float a[8] = {0.f, 0.f, 0.f, 0.f, 0.f, 0.f, 0.f, 0.f};
  int rel = 8, g = 0;
  unsigned q = 0;
  if (active) {
    unsigned n = idx / 10u;
    q = idx - n * 10u;
    gather_sum(a, hs + 8u * q, n, ell, rowptr, ssrc);
    float di = dinv[n];
#pragma unroll
    for (int j = 0; j < 8; ++j) {
      int col = q * 8 + j;
      float bv = (col < 78) ? b[boff + col] : 0.f;
      a[j] = fmaxf(fmaf(di, a[j], bv), 0.f);
    }
    g = batch[n];
    rel = g - sgbase;
  }
  if (active && rel < 8) {
#pragma unroll
    for (int j = 0; j < 8; ++j) atomicAdd(&part[rel][q * 8 + j], a[j]);
  } else if (active) {
#pragma unroll
    for (int j = 0; j < 8; ++j)
      atomicAdd(&gsum[(size_t)g * 320 + coff + q * 8 + j], a[j]);
  }
  __syncthreads();
  for (int i = tid; i < 640; i += 256) {
    float v = (&part[0][0])[i];
    if (v != 0.f) {
      int r = i / 80, col = i - r * 80;
      atomicAdd(&gsum[(size_t)(sgbase + r) * 320 + coff + col], v);
    }
  }
}

// GA[g, chunk96 layout 384] = f16(gsum[g, chunk80 layout] / cnt), pads zero
__global__ __launch_bounds__(256) void ga_convert(
    const float* __restrict__ gsum, const int* __restrict__ gstart,
    _Float16* __restrict__ GA) {
  int i = blockIdx.x * 256 + threadIdx.x;
  if (i >= N_GRAPHS * 192) return;
  int g = i / 192, c2 = i - g * 192;
  int col = 2 * c2;
  int chunk = col / 96, j = col - chunk * 96;
  float gi = 1.0f / fmaxf((float)(gstart[g + 1] - gstart[g]), 1.0f);
  float v0 = (j < 78) ? gsum[(size_t)g * 320 + chunk * 80 + j] * gi : 0.f;
  float v1 = (j + 1 < 78) ? gsum[(size_t)g * 320 + chunk * 80 + j + 1] * gi : 0.f;
  *reinterpret_cast<__half2*>(GA + (size_t)g * 384 + col) = __floats2half2_rn(v0, v1);
}

extern "C" void kernel_launch(void* const* d_in, const int* in_sizes, int n_in,
                              void* d_out, int out_size, void* d_ws, size_t ws_size,
                              hipStream_t stream) {
  const float* x   = (const float*)d_in[0];
  const int* ei    = (const int*)d_in[1];
  const int* batch = (const int*)d_in[2];
  const float* W1 = (const float*)d_in[3];
  const float* b1 = (const float*)d_in[4];
  const float* W2 = (const float*)d_in[5];
  const float* b2 = (const float*)d_in[6];
  const float* W3 = (const float*)d_in[7];
  const float* b3 = (const float*)d_in[8];
  const float* fW1 = (const float*)d_in[9];
  const float* fb1 = (const float*)d_in[10];
  const float* fW2 = (const float*)d_in[11];
  const float* fb2 = (const float*)d_in[12];
  float* out = (float*)d_out;

  const int Nn = N_NODES, E = N_EDGES, G = N_GRAPHS;
  const int* src = ei;
  const int* dst = ei + E;

  // ---- workspace layout (~428 MB) ----
  // P0 aliases AGG1h (dead during L3); P1 = old HSh plane (fc1 aliases after L3);
  // Xh aliases AGG2h. Pad columns never zeroed: they only multiply zero-padded
  // weight rows or land in ignored gsum/GA columns (0xAA is finite fp16).
  _Float16* AGG2h = (_Float16*)d_ws;                      // [N,192]
  _Float16* Xh    = AGG2h;                                // [N,96]
  _Float16* AGG1h = AGG2h + (size_t)Nn * 192;             // [N,96]; P0 alias
  _Float16* P0    = AGG1h;                                // [N,80] plane 0 (L3)
  _Float16* P1    = AGG1h + (size_t)Nn * 96;              // [N,80] plane 1 / hs chunk
  _Float16* fc1   = P1;                                   // [G,1056] (after last agg_pool)
  _Float16* GA    = P1 + (size_t)Nn * 80;                 // [G,384] chunk96
  float*    gsum  = (float*)(GA + (size_t)G * 384);       // [G,320] f32
  _Float16* W1T   = (_Float16*)(gsum + (size_t)G * 320);  // [80][96]
  _Float16* W2T   = W1T + 80 * 96;                        // [160][96]
  _Float16* W3T   = W2T + 160 * 96;                       // [320][192] chunk96
  _Float16* fW1T  = W3T + 320 * 192;                      // [1040][384] chunk96
  _Float16* fW2T  = fW1T + (size_t)1040 * 384;            // [160][1056]
  float* dinv     = (float*)(fW2T + (size_t)160 * 1056);  // [N]
  int* rowptr     = (int*)(dinv + Nn);                    // [N+1]
  int* cur        = rowptr + Nn + 1;                      // [N]
  int* ssrc       = cur + Nn;                             // [E]
  int* partials   = ssrc + E;                             // [512]
  int* gstart     = partials + 512;                       // [G+1]
  int4* ell = (int4*)(((uintptr_t)(gstart + G + 1) + 15) & ~(uintptr_t)15);  // [N]

  dim3 blk(256);
  const int gN10 = (int)(((unsigned)Nn * 10u + 255u) / 256u);
  const dim3 nodeGrid(1, (Nn + 127) / 128);
  const dim3 pairGrid(2, (Nn + 127) / 128);
  const int NB = (Nn + 1023) / 1024;  // 489
  const size_t PSTRIDE = (size_t)Nn * 96;  // P1 - P0 in f16 elems

  // ---- CSR build (dst-sorted src list) + ELL + graph starts ----
  fill_u32<<<(Nn + 255) / 256, blk, 0, stream>>>((unsigned*)cur, 0u, Nn);
  hist_dst<<<(E + 255) / 256, blk, 0, stream>>>(dst, cur, E);
  scanA<<<NB, blk, 0, stream>>>(cur, rowptr, partials, Nn);
  scanB<<<1, 512, 0, stream>>>(partials, NB);
  scanC<<<(Nn + 255) / 256, blk, 0, stream>>>(rowptr, partials, cur, Nn, E);
  dinv_k<<<(Nn + 255) / 256, blk, 0, stream>>>(rowptr, dinv, Nn);
  bucket<<<(E + 255) / 256, blk, 0, stream>>>(src, dst, cur, ssrc, E);
  ell_build<<<(Nn + 255) / 256, blk, 0, stream>>>(rowptr, ssrc, ell, Nn);
  graph_starts<<<(Nn + 256) / 256, blk, 0, stream>>>(batch, gstart, Nn);

  // ---- fp16 transposed weights ----
  wt_conv<0><<<(80 * 96 + 255) / 256, blk, 0, stream>>>(W1, W1T, 78, 78, 78, 96, 80 * 96);
  wt_conv<0><<<(160 * 96 + 255) / 256, blk, 0, stream>>>(W2, W2T, 78, 156, 156, 96, 160 * 96);
  wt_conv<1><<<(320 * 192 + 255) / 256, blk, 0, stream>>>(W3, W3T, 156, 312, 312, 192, 320 * 192);
  wt_conv<1><<<(1040 * 384 + 255) / 256, blk, 0, stream>>>(fW1, fW1T, 312, 1024, 1024, 384, 1040 * 384);
  wt_conv<0><<<(160 * 1056 + 255) / 256, blk, 0, stream>>>(fW2, fW2T, 1024, 128, 128, 1056, 160 * 1056);

  // ---- zero gsum; x -> f16 [N,96] ----
  fill_u32<<<(G * 320 + 255) / 256, blk, 0, stream>>>((unsigned*)gsum, 0u, G * 320);
  xconv<<<(int)(((unsigned)Nn * 48u + 255u) / 256u), blk, 0, stream>>>(x, Xh);

  // ---- layer 1 ----
  gemm_direct<96, 0, 1, 0><<<nodeGrid, blk, 0, stream>>>(Xh, W1T, P1, dinv, nullptr, Nn, 78, 80, 0);
  aggregate16B<<<gN10, blk, 0, stream>>>(P1, ell, rowptr, ssrc, dinv, b1, AGG1h, 96, 0, 0);

  // ---- layer 2 (2 chunks of 78 -> AGG2h chunk-strided) ----
  for (int c = 0; c < 2; ++c) {
    gemm_direct<96, 0, 1, 0><<<nodeGrid, blk, 0, stream>>>(
        AGG1h, W2T + (size_t)(78 * c) * 96, P1, dinv, nullptr, Nn, 78, 80, 0);
    aggregate16B<<<gN10, blk, 0, stream>>>(P1, ell, rowptr, ssrc, dinv, b2, AGG2h, 192, 78 * c, 96 * c);
  }

  // ---- layer 3: 2 merged plane-GEMMs (chunks 2p, 2p+1 -> P0, P1) + fused pools ----
  for (int p = 0; p < 2; ++p) {
    gemm_direct<192, 0, 1, 1><<<pairGrid, blk, 0, stream>>>(
        AGG2h, W3T + (size_t)(156 * p) * 192, P0, dinv, nullptr, Nn, 78, 80, PSTRIDE);
    agg_pool<<<gN10, blk, 0, stream>>>(P0, ell, rowptr, ssrc, dinv, b3, 156 * p, batch, gsum, 160 * p);
    agg_pool<<<gN10, blk, 0, stream>>>(P1, ell, rowptr, ssrc, dinv, b3, 156 * p + 78, batch, gsum, 160 * p + 80);
  }

  // ---- mean-pool scale -> GA f16 (chunk96 layout, pads zero) ----
  ga_convert<<<(G * 192 + 255) / 256, blk, 0, stream>>>(gsum, gstart, GA);

  // ---- FC1: relu(GA @ fW1 + fb1) -> fc1 f16 (B staged in 60 KB LDS) ----
  {
    dim3 g((1024 + 79) / 80, (G + 127) / 128);  // 13 x 157
    gemm_direct<384, 1, 1, 0><<<g, blk, 0, stream>>>(GA, fW1T, fc1, nullptr, fb1, G, 1024, 1056, 0);
  }
  // ---- FC2: out = fc1 @ fW2 + fb2 (f32) ----
  {
    dim3 g((128 + 79) / 80, (G + 127) / 128);  // 2 x 157
    gemm_direct<1056, 2, 0, 0><<<g, blk, 0, stream>>>(fc1, fW2T, out, nullptr, fb2, G, 128, 128, 0);
  }
}

// Round 12
// 1401.702 us; speedup vs baseline: 1.4466x; 1.4466x over previous
//
#include <hip/hip_runtime.h>
#include <hip/hip_fp16.h>

#define N_NODES 500000
#define N_EDGES 1000000
#define N_GRAPHS 20000

typedef _Float16 f16x8 __attribute__((ext_vector_type(8)));
typedef float f32x4 __attribute__((ext_vector_type(4)));

__global__ __launch_bounds__(256) void fill_u32(unsigned* p, unsigned v, int n) {
  int i = blockIdx.x * 256 + threadIdx.x;
  if (i < n) p[i] = v;
}

__global__ __launch_bounds__(256) void hist_dst(const int* __restrict__ dst, int* cnt, int e) {
  int i = blockIdx.x * 256 + threadIdx.x;
  if (i < e) atomicAdd(&cnt[dst[i]], 1);
}

// ---- 2-level exclusive scan over deg[N] (1024 elems/block) ----
__global__ __launch_bounds__(256) void scanA(const int* __restrict__ deg, int* __restrict__ loc,
                                             int* __restrict__ partials, int n) {
  __shared__ int ts[256];
  int b = blockIdx.x, t = threadIdx.x;
  int base = b * 1024 + t * 4;
  int v[4], s = 0;
#pragma unroll
  for (int j = 0; j < 4; ++j) {
    v[j] = (base + j < n) ? deg[base + j] : 0;
    s += v[j];
  }
  ts[t] = s;
  __syncthreads();
  for (int off = 1; off < 256; off <<= 1) {
    int x = (t >= off) ? ts[t - off] : 0;
    __syncthreads();
    ts[t] += x;
    __syncthreads();
  }
  if (t == 255) partials[b] = ts[255];
  int run = ts[t] - s;  // exclusive
#pragma unroll
  for (int j = 0; j < 4; ++j) {
    if (base + j < n) loc[base + j] = run;
    run += v[j];
  }
}

__global__ __launch_bounds__(512) void scanB(int* partials, int nb) {
  __shared__ int s[512];
  int t = threadIdx.x;
  s[t] = (t < nb) ? partials[t] : 0;
  __syncthreads();
  if (t == 0) {
    int run = 0;
    for (int i = 0; i < nb; ++i) { int v = s[i]; s[i] = run; run += v; }
  }
  __syncthreads();
  if (t < nb) partials[t] = s[t];
}

__global__ __launch_bounds__(256) void scanC(int* __restrict__ rowptr, const int* __restrict__ partials,
                                             int* __restrict__ cur, int n, int e) {
  int i = blockIdx.x * 256 + threadIdx.x;
  if (i < n) {
    int v = rowptr[i] + partials[i >> 10];
    rowptr[i] = v;
    cur[i] = v;
  }
  if (i == 0) rowptr[n] = e;
}

__global__ __launch_bounds__(256) void dinv_k(const int* __restrict__ rowptr, float* dinv, int n) {
  int i = blockIdx.x * 256 + threadIdx.x;
  if (i < n) dinv[i] = rsqrtf(1.0f + (float)(rowptr[i + 1] - rowptr[i]));
}

__global__ __launch_bounds__(256) void bucket(const int* __restrict__ src, const int* __restrict__ dst,
                                              int* __restrict__ cur, int* __restrict__ ssrc, int e) {
  int i = blockIdx.x * 256 + threadIdx.x;
  if (i < e) ssrc[atomicAdd(&cur[dst[i]], 1)] = src[i];
}

// ell[n] = {deg, s0, s1, s2}
__global__ __launch_bounds__(256) void ell_build(const int* __restrict__ rowptr,
                                                 const int* __restrict__ ssrc,
                                                 int4* __restrict__ ell, int n) {
  int i = blockIdx.x * 256 + threadIdx.x;
  if (i >= n) return;
  int r0 = rowptr[i], r1 = rowptr[i + 1];
  int deg = r1 - r0;
  int4 e;
  e.x = deg;
  e.y = (deg > 0) ? ssrc[r0] : 0;
  e.z = (deg > 1) ? ssrc[r0 + 1] : 0;
  e.w = (deg > 2) ? ssrc[r0 + 2] : 0;
  ell[i] = e;
}

// gstart[g] = first node index of graph g (batch sorted); gstart[G] = N
__global__ __launch_bounds__(256) void graph_starts(const int* __restrict__ batch,
                                                    int* __restrict__ gstart, int n) {
  int i = blockIdx.x * 256 + threadIdx.x;
  if (i < n) {
    int b = batch[i];
    int bp = (i == 0) ? -1 : batch[i - 1];
    for (int g = bp + 1; g <= b; ++g) gstart[g] = i;
  } else if (i == n) {
    int bl = batch[n - 1];
    for (int g = bl + 1; g <= N_GRAPHS; ++g) gstart[g] = n;
  }
}

// WT[c][k'] = f16(W[k][c]); CW>0: chunk layout, k = 78*(k'/CW) + k'%CW, valid (k'%CW)<78
template <int CW>
__global__ __launch_bounds__(256) void wt_conv(const float* __restrict__ W, _Float16* __restrict__ WT,
                                               int K, int Nout, int ldw, int KP, int total) {
  int i = blockIdx.x * 256 + threadIdx.x;
  if (i >= total) return;
  int c = i / KP, kp = i - c * KP;
  int k; bool valid;
  if (CW) { int blk = kp / CW, r = kp - blk * CW; k = blk * 78 + r; valid = (r < 78) && (k < K); }
  else { k = kp; valid = kp < K; }
  WT[i] = (valid && c < Nout) ? (_Float16)W[(size_t)k * ldw + c] : (_Float16)0.f;
}

// Xh[n, 0:96] = f16(x[n, 0:78]), zero pad
__global__ __launch_bounds__(256) void xconv(const float* __restrict__ xin, _Float16* __restrict__ Xh) {
  unsigned idx = blockIdx.x * 256u + threadIdx.x;
  if (idx >= (unsigned)N_NODES * 48u) return;
  unsigned n = idx / 48u, c2 = idx - n * 48u;
  __half2 h = __floats2half2_rn(0.f, 0.f);
  if (c2 < 39u) {
    float2 v = *reinterpret_cast<const float2*>(xin + (size_t)n * 78 + 2 * c2);
    h = __floats2half2_rn(v.x, v.y);
  }
  *reinterpret_cast<__half2*>((__half*)Xh + (size_t)n * 96 + 2 * c2) = h;
}

// Direct-register MFMA GEMM. in [M,KP] f16; WT [*,KP] f16 pre-transposed. Tile 128x80.
// BLDS=1: stage B in LDS fragment-linear (conflict-free), single barrier.
// PLANE=1: blockIdx.x = output chunk; out16 += x*planeStride (col offset), WT += x*78*KP.
// OUT_MODE 0: v*rs[row] -> f16 ; 1: relu(v+bo) -> f16 ; 2: v+bo -> f32
template <int KP, int OUT_MODE, int BLDS, int PLANE>
__global__ __launch_bounds__(256) void gemm_direct(
    const _Float16* __restrict__ in, const _Float16* __restrict__ WT,
    void* __restrict__ outp, const float* __restrict__ rs, const float* __restrict__ bo,
    int M, int Nout, int LDO, size_t planeStride) {
  constexpr int NS = KP / 32;
  __shared__ _Float16 Bs[BLDS ? 5 * NS * 64 * 8 : 8];
  const int tid = threadIdx.x;
  const int lane = tid & 63;
  const int wid = tid >> 6;
  const int row0 = blockIdx.y * 128;
  const int col0 = PLANE ? 0 : blockIdx.x * 80;
  const _Float16* wt = WT + (size_t)(PLANE ? blockIdx.x * 78 : col0) * KP;
  _Float16* out16 = (_Float16*)outp + (PLANE ? (size_t)blockIdx.x * planeStride : 0);
  float* out32 = (float*)outp;
  const int koff = (lane >> 4) * 8;
  const int gr0 = row0 + wid * 32 + (lane & 15);
  const bool v0 = gr0 < M, v1 = (gr0 + 16) < M;
  const _Float16* a0 = in + (size_t)gr0 * KP + koff;
  const _Float16* a1 = a0 + (size_t)16 * KP;
  const _Float16* bp = wt + (size_t)(lane & 15) * KP + koff;

  if (BLDS) {
    for (int i = tid; i < 5 * NS * 64; i += 256) {
      int l = i & 63;
      int nf = (i >> 6) % 5;
      int s = i / 320;
      int r = nf * 16 + (l & 15);
      int k = s * 32 + ((l >> 4) << 3);
      *reinterpret_cast<uint4*>(&Bs[(size_t)i * 8]) =
          *reinterpret_cast<const uint4*>(wt + (size_t)r * KP + k);
    }
    __syncthreads();
  }

  const f16x8 zf = {0, 0, 0, 0, 0, 0, 0, 0};
  const f32x4 z4 = {0.f, 0.f, 0.f, 0.f};
  f32x4 acc[2][5];
#pragma unroll
  for (int a = 0; a < 2; ++a)
#pragma unroll
    for (int b = 0; b < 5; ++b) acc[a][b] = z4;

#pragma unroll
  for (int s = 0; s < NS; ++s) {
    f16x8 af0 = v0 ? *reinterpret_cast<const f16x8*>(a0 + s * 32) : zf;
    f16x8 af1 = v1 ? *reinterpret_cast<const f16x8*>(a1 + s * 32) : zf;
    f16x8 bf[5];
#pragma unroll
    for (int nf = 0; nf < 5; ++nf) {
      if (BLDS)
        bf[nf] = *reinterpret_cast<const f16x8*>(&Bs[((size_t)(s * 5 + nf) * 64 + lane) * 8]);
      else
        bf[nf] = *reinterpret_cast<const f16x8*>(bp + (size_t)nf * 16 * KP + s * 32);
    }
#pragma unroll
    for (int nf = 0; nf < 5; ++nf) {
      acc[0][nf] = __builtin_amdgcn_mfma_f32_16x16x32_f16(af0, bf[nf], acc[0][nf], 0, 0, 0);
      acc[1][nf] = __builtin_amdgcn_mfma_f32_16x16x32_f16(af1, bf[nf], acc[1][nf], 0, 0, 0);
    }
  }

  // epilogue: C/D col=lane&15, row=(lane>>4)*4+reg
#pragma unroll
  for (int rf = 0; rf < 2; ++rf) {
#pragma unroll
    for (int j = 0; j < 4; ++j) {
      int gr = row0 + wid * 32 + rf * 16 + (lane >> 4) * 4 + j;
      if (gr >= M) continue;
      float sc = (OUT_MODE == 0) ? rs[gr] : 0.f;
#pragma unroll
      for (int nf = 0; nf < 5; ++nf) {
        int oc = col0 + nf * 16 + (lane & 15);
        if (oc >= Nout) continue;
        float v = acc[rf][nf][j];
        if (OUT_MODE == 0) {
          out16[(size_t)gr * LDO + oc] = (_Float16)(v * sc);
        } else if (OUT_MODE == 1) {
          out16[(size_t)gr * LDO + oc] = (_Float16)fmaxf(v + bo[oc], 0.f);
        } else {
          out32[(size_t)gr * LDO + oc] = v + bo[oc];
        }
      }
    }
  }
}

__device__ inline void acc8(float* a, uint4 v) {
  const __half2* h = reinterpret_cast<const __half2*>(&v);
#pragma unroll
  for (int j = 0; j < 4; ++j) {
    float2 f = __half22float2(h[j]);
    a[2 * j] += f.x;
    a[2 * j + 1] += f.y;
  }
}

// segment-sum gather; hs rows have stride 160 f16 from hbase
__device__ inline void gather_sum(float* a, const _Float16* hbase, unsigned n,
                                  const int4* __restrict__ ell,
                                  const int* __restrict__ rowptr,
                                  const int* __restrict__ ssrc) {
  int4 e = ell[n];
  const int deg = e.x;
  uint4 sv = *reinterpret_cast<const uint4*>(hbase + (size_t)n * 160);
  uint4 g0, g1, g2;
  if (deg > 0) g0 = *reinterpret_cast<const uint4*>(hbase + (size_t)e.y * 160);
  if (deg > 1) g1 = *reinterpret_cast<const uint4*>(hbase + (size_t)e.z * 160);
  if (deg > 2) g2 = *reinterpret_cast<const uint4*>(hbase + (size_t)e.w * 160);
  {
    const __half2* h = reinterpret_cast<const __half2*>(&sv);
#pragma unroll
    for (int j = 0; j < 4; ++j) {
      float2 f = __half22float2(h[j]);
      a[2 * j] = f.x;
      a[2 * j + 1] = f.y;
    }
  }
  if (deg > 0) acc8(a, g0);
  if (deg > 1) acc8(a, g1);
  if (deg > 2) acc8(a, g2);
  if (deg > 3) {
    int r = rowptr[n] + 3, r1 = r + deg - 3;
    for (; r + 2 <= r1; r += 2) {
      uint4 va = *reinterpret_cast<const uint4*>(hbase + (size_t)ssrc[r] * 160);
      uint4 vb = *reinterpret_cast<const uint4*>(hbase + (size_t)ssrc[r + 1] * 160);
      acc8(a, va);
      acc8(a, vb);
    }
    if (r < r1) {
      uint4 va = *reinterpret_cast<const uint4*>(hbase + (size_t)ssrc[r] * 160);
      acc8(a, va);
    }
  }
}

// Fused segment-sum + transform over NCHUNK 80-wide chunks of hs [N,160].
// Thread (n, c, sub): reads hs[n, rcoff + c*80 + sub*8 ..+8], writes
// dsth[n*ldo + c*ocs + sub*8] = relu(dinv*(self+gather) + b[boff + c*78 + f]), pad f>=78 -> bias 0.
template <int NCHUNK>
__global__ __launch_bounds__(256) void aggregateN(
    const _Float16* __restrict__ hs, const int4* __restrict__ ell,
    const int* __restrict__ rowptr, const int* __restrict__ ssrc,
    const float* __restrict__ dinv, const float* __restrict__ b,
    _Float16* __restrict__ dsth, int ldo, int ocs, int boff, int rcoff) {
  constexpr unsigned T = NCHUNK * 10;
  unsigned idx = blockIdx.x * 256u + threadIdx.x;
  if (idx >= (unsigned)N_NODES * T) return;
  unsigned n = idx / T, q = idx - n * T;
  unsigned c = q / 10, sub = q - c * 10;
  float a[8];
  gather_sum(a, hs + rcoff + c * 80 + sub * 8, n, ell, rowptr, ssrc);
  float di = dinv[n];
  _Float16 ov[8];
#pragma unroll
  for (int j = 0; j < 8; ++j) {
    int f = sub * 8 + j;
    float bv = (f < 78) ? b[boff + c * 78 + f] : 0.f;
    ov[j] = (_Float16)fmaxf(fmaf(di, a[j], bv), 0.f);
  }
  *reinterpret_cast<uint4*>(dsth + (size_t)n * ldo + c * ocs + sub * 8) =
      *reinterpret_cast<const uint4*>(ov);
}

// Mean-pool over contiguous node range: GA[g*320 + coffGA + 2q..] = (1/cnt) Σ_n TR[n*80 + 2q..]
__global__ __launch_bounds__(256) void pool_seq(
    const _Float16* __restrict__ TR, const int* __restrict__ gstart,
    _Float16* __restrict__ GA, int coffGA) {
  unsigned idx = blockIdx.x * 256u + threadIdx.x;
  if (idx >= (unsigned)N_GRAPHS * 40u) return;
  unsigned g = idx / 40u, q = idx - g * 40u;
  int jj = 2 * q;
  if (jj >= 78) return;
  int n0 = gstart[g], n1 = gstart[g + 1];
  const __half* base = (const __half*)TR + jj;
  float ax = 0.f, ay = 0.f, bx = 0.f, by = 0.f;
  int n = n0;
  for (; n + 2 <= n1; n += 2) {
    __half2 va = *reinterpret_cast<const __half2*>(base + (size_t)n * 80);
    __half2 vb = *reinterpret_cast<const __half2*>(base + (size_t)(n + 1) * 80);
    ax += __half2float(va.x); ay += __half2float(va.y);
    bx += __half2float(vb.x); by += __half2float(vb.y);
  }
  if (n < n1) {
    __half2 va = *reinterpret_cast<const __half2*>(base + (size_t)n * 80);
    ax += __half2float(va.x); ay += __half2float(va.y);
  }
  float gi = 1.0f / fmaxf((float)(n1 - n0), 1.0f);
  *reinterpret_cast<__half2*>(GA + (size_t)g * 320 + coffGA + jj) =
      __floats2half2_rn((ax + bx) * gi, (ay + by) * gi);
}

extern "C" void kernel_launch(void* const* d_in, const int* in_sizes, int n_in,
                              void* d_out, int out_size, void* d_ws, size_t ws_size,
                              hipStream_t stream) {
  const float* x   = (const float*)d_in[0];
  const int* ei    = (const int*)d_in[1];
  const int* batch = (const int*)d_in[2];
  const float* W1 = (const float*)d_in[3];
  const float* b1 = (const float*)d_in[4];
  const float* W2 = (const float*)d_in[5];
  const float* b2 = (const float*)d_in[6];
  const float* W3 = (const float*)d_in[7];
  const float* b3 = (const float*)d_in[8];
  const float* fW1 = (const float*)d_in[9];
  const float* fb1 = (const float*)d_in[10];
  const float* fW2 = (const float*)d_in[11];
  const float* fb2 = (const float*)d_in[12];
  float* out = (float*)d_out;

  const int Nn = N_NODES, E = N_EDGES, G = N_GRAPHS;
  const int* src = ei;
  const int* dst = ei + E;

  // ---- workspace layout (~450 MB) ----
  // AGG2h [N][2][80] chunk80; Xh [N,96] aliases it (dead after L1 gemm).
  // AGG1h [N,96]; TR [N,80] aliases it (L3 only, AGG1h dead then).
  // HS2 [N,160]: gemm output planes; fc1 [G,1056] aliases after L3.
  _Float16* AGG2h = (_Float16*)d_ws;                      // [N,160]
  _Float16* Xh    = AGG2h;                                // [N,96]
  _Float16* AGG1h = AGG2h + (size_t)Nn * 160;             // [N,96]
  _Float16* TR    = AGG1h;                                // [N,80] (L3)
  _Float16* HS2   = AGG1h + (size_t)Nn * 96;              // [N,160]
  _Float16* fc1   = HS2;                                  // [G,1056] (after L3)
  _Float16* GA    = HS2 + (size_t)Nn * 160;               // [G,320] chunk80
  _Float16* W1T   = GA + (size_t)G * 320;                 // [80][96]
  _Float16* W2T   = W1T + 80 * 96;                        // [160][96]
  _Float16* W3T   = W2T + 160 * 96;                       // [320][160] chunk80
  _Float16* fW1T  = W3T + 320 * 160;                      // [1040][320] chunk80
  _Float16* fW2T  = fW1T + (size_t)1040 * 320;            // [160][1056]
  float* dinv     = (float*)(fW2T + (size_t)160 * 1056);  // [N]
  int* rowptr     = (int*)(dinv + Nn);                    // [N+1]
  int* cur        = rowptr + Nn + 1;                      // [N]
  int* ssrc       = cur + Nn;                             // [E]
  int* partials   = ssrc + E;                             // [512]
  int* gstart     = partials + 512;                       // [G+1]
  int4* ell = (int4*)(((uintptr_t)(gstart + G + 1) + 15) & ~(uintptr_t)15);  // [N]

  dim3 blk(256);
  const int gN10 = (int)(((unsigned)Nn * 10u + 255u) / 256u);
  const int gN20 = (int)(((unsigned)Nn * 20u + 255u) / 256u);
  const int gG40 = (int)(((unsigned)G * 40u + 255u) / 256u);
  const dim3 nodeGrid(1, (Nn + 127) / 128);
  const dim3 pairGrid(2, (Nn + 127) / 128);
  const int NB = (Nn + 1023) / 1024;  // 489

  // ---- CSR build + ELL + graph starts ----
  fill_u32<<<(Nn + 255) / 256, blk, 0, stream>>>((unsigned*)cur, 0u, Nn);
  hist_dst<<<(E + 255) / 256, blk, 0, stream>>>(dst, cur, E);
  scanA<<<NB, blk, 0, stream>>>(cur, rowptr, partials, Nn);
  scanB<<<1, 512, 0, stream>>>(partials, NB);
  scanC<<<(Nn + 255) / 256, blk, 0, stream>>>(rowptr, partials, cur, Nn, E);
  dinv_k<<<(Nn + 255) / 256, blk, 0, stream>>>(rowptr, dinv, Nn);
  bucket<<<(E + 255) / 256, blk, 0, stream>>>(src, dst, cur, ssrc, E);
  ell_build<<<(Nn + 255) / 256, blk, 0, stream>>>(rowptr, ssrc, ell, Nn);
  graph_starts<<<(Nn + 256) / 256, blk, 0, stream>>>(batch, gstart, Nn);

  // ---- fp16 transposed weights ----
  wt_conv<0><<<(80 * 96 + 255) / 256, blk, 0, stream>>>(W1, W1T, 78, 78, 78, 96, 80 * 96);
  wt_conv<0><<<(160 * 96 + 255) / 256, blk, 0, stream>>>(W2, W2T, 78, 156, 156, 96, 160 * 96);
  wt_conv<80><<<(320 * 160 + 255) / 256, blk, 0, stream>>>(W3, W3T, 156, 312, 312, 160, 320 * 160);
  wt_conv<80><<<(1040 * 320 + 255) / 256, blk, 0, stream>>>(fW1, fW1T, 312, 1024, 1024, 320, 1040 * 320);
  wt_conv<0><<<(160 * 1056 + 255) / 256, blk, 0, stream>>>(fW2, fW2T, 1024, 128, 128, 1056, 160 * 1056);

  // ---- x -> f16 [N,96] ----
  xconv<<<(int)(((unsigned)Nn * 48u + 255u) / 256u), blk, 0, stream>>>(x, Xh);

  // ---- layer 1: gemm -> HS2 plane0 ; aggregate (1 chunk) -> AGG1h ----
  gemm_direct<96, 0, 1, 0><<<nodeGrid, blk, 0, stream>>>(Xh, W1T, HS2, dinv, nullptr, Nn, 78, 160, 0);
  aggregateN<1><<<gN10, blk, 0, stream>>>(HS2, ell, rowptr, ssrc, dinv, b1, AGG1h, 96, 96, 0, 0);

  // ---- layer 2: merged plane-pair gemm -> HS2[2][80] ; 1 aggregate (2 chunks) -> AGG2h ----
  gemm_direct<96, 0, 1, 1><<<pairGrid, blk, 0, stream>>>(AGG1h, W2T, HS2, dinv, nullptr, Nn, 78, 160, 80);
  aggregateN<2><<<gN20, blk, 0, stream>>>(HS2, ell, rowptr, ssrc, dinv, b2, AGG2h, 160, 80, 0, 0);

  // ---- layer 3: 2 passes x {plane-pair gemm; per-chunk aggregate -> TR -> pool} ----
  for (int p = 0; p < 2; ++p) {
    gemm_direct<160, 0, 1, 1><<<pairGrid, blk, 0, stream>>>(
        AGG2h, W3T + (size_t)(156 * p) * 160, HS2, dinv, nullptr, Nn, 78, 160, 80);
    for (int cc = 0; cc < 2; ++cc) {
      aggregateN<1><<<gN10, blk, 0, stream>>>(HS2, ell, rowptr, ssrc, dinv, b3, TR,
                                              80, 80, 156 * p + 78 * cc, 80 * cc);
      pool_seq<<<gG40, blk, 0, stream>>>(TR, gstart, GA, (2 * p + cc) * 80);
    }
  }

  // ---- FC1: relu(GA @ fW1 + fb1) -> fc1 f16 (B staged in 50 KB LDS) ----
  {
    dim3 g((1024 + 79) / 80, (G + 127) / 128);  // 13 x 157
    gemm_direct<320, 1, 1, 0><<<g, blk, 0, stream>>>(GA, fW1T, fc1, nullptr, fb1, G, 1024, 1056, 0);
  }
  // ---- FC2: out = fc1 @ fW2 + fb2 (f32) ----
  {
    dim3 g((128 + 79) / 80, (G + 127) / 128);  // 2 x 157
    gemm_direct<1056, 2, 0, 0><<<g, blk, 0, stream>>>(fc1, fW2T, out, nullptr, fb2, G, 128, 128, 0);
  }
}

// Round 13
// 1375.688 us; speedup vs baseline: 1.4740x; 1.0189x over previous
//
#include <hip/hip_runtime.h>
#include <hip/hip_fp16.h>

#define N_NODES 500000
#define N_EDGES 1000000
#define N_GRAPHS 20000

typedef _Float16 f16x8 __attribute__((ext_vector_type(8)));
typedef float f32x4 __attribute__((ext_vector_type(4)));

__global__ __launch_bounds__(256) void fill_u32(unsigned* p, unsigned v, int n) {
  int i = blockIdx.x * 256 + threadIdx.x;
  if (i < n) p[i] = v;
}

__global__ __launch_bounds__(256) void hist_dst(const int* __restrict__ dst, int* cnt, int e) {
  int i = blockIdx.x * 256 + threadIdx.x;
  if (i < e) atomicAdd(&cnt[dst[i]], 1);
}

// ---- 2-level exclusive scan over deg[N] (1024 elems/block) ----
__global__ __launch_bounds__(256) void scanA(const int* __restrict__ deg, int* __restrict__ loc,
                                             int* __restrict__ partials, int n) {
  __shared__ int ts[256];
  int b = blockIdx.x, t = threadIdx.x;
  int base = b * 1024 + t * 4;
  int v[4], s = 0;
#pragma unroll
  for (int j = 0; j < 4; ++j) {
    v[j] = (base + j < n) ? deg[base + j] : 0;
    s += v[j];
  }
  ts[t] = s;
  __syncthreads();
  for (int off = 1; off < 256; off <<= 1) {
    int x = (t >= off) ? ts[t - off] : 0;
    __syncthreads();
    ts[t] += x;
    __syncthreads();
  }
  if (t == 255) partials[b] = ts[255];
  int run = ts[t] - s;  // exclusive
#pragma unroll
  for (int j = 0; j < 4; ++j) {
    if (base + j < n) loc[base + j] = run;
    run += v[j];
  }
}

__global__ __launch_bounds__(512) void scanB(int* partials, int nb) {
  __shared__ int s[512];
  int t = threadIdx.x;
  s[t] = (t < nb) ? partials[t] : 0;
  __syncthreads();
  if (t == 0) {
    int run = 0;
    for (int i = 0; i < nb; ++i) { int v = s[i]; s[i] = run; run += v; }
  }
  __syncthreads();
  if (t < nb) partials[t] = s[t];
}

__global__ __launch_bounds__(256) void scanC(int* __restrict__ rowptr, const int* __restrict__ partials,
                                             int* __restrict__ cur, int n, int e) {
  int i = blockIdx.x * 256 + threadIdx.x;
  if (i < n) {
    int v = rowptr[i] + partials[i >> 10];
    rowptr[i] = v;
    cur[i] = v;
  }
  if (i == 0) rowptr[n] = e;
}

__global__ __launch_bounds__(256) void dinv_k(const int* __restrict__ rowptr, float* dinv, int n) {
  int i = blockIdx.x * 256 + threadIdx.x;
  if (i < n) dinv[i] = rsqrtf(1.0f + (float)(rowptr[i + 1] - rowptr[i]));
}

__global__ __launch_bounds__(256) void bucket(const int* __restrict__ src, const int* __restrict__ dst,
                                              int* __restrict__ cur, int* __restrict__ ssrc, int e) {
  int i = blockIdx.x * 256 + threadIdx.x;
  if (i < e) ssrc[atomicAdd(&cur[dst[i]], 1)] = src[i];
}

// ell[n] = {deg, s0, s1, s2}
__global__ __launch_bounds__(256) void ell_build(const int* __restrict__ rowptr,
                                                 const int* __restrict__ ssrc,
                                                 int4* __restrict__ ell, int n) {
  int i = blockIdx.x * 256 + threadIdx.x;
  if (i >= n) return;
  int r0 = rowptr[i], r1 = rowptr[i + 1];
  int deg = r1 - r0;
  int4 e;
  e.x = deg;
  e.y = (deg > 0) ? ssrc[r0] : 0;
  e.z = (deg > 1) ? ssrc[r0 + 1] : 0;
  e.w = (deg > 2) ? ssrc[r0 + 2] : 0;
  ell[i] = e;
}

// gstart[g] = first node index of graph g (batch sorted); gstart[G] = N
__global__ __launch_bounds__(256) void graph_starts(const int* __restrict__ batch,
                                                    int* __restrict__ gstart, int n) {
  int i = blockIdx.x * 256 + threadIdx.x;
  if (i < n) {
    int b = batch[i];
    int bp = (i == 0) ? -1 : batch[i - 1];
    for (int g = bp + 1; g <= b; ++g) gstart[g] = i;
  } else if (i == n) {
    int bl = batch[n - 1];
    for (int g = bl + 1; g <= N_GRAPHS; ++g) gstart[g] = n;
  }
}

// WT[c][k'] = f16(W[k][c]); CW>0: chunk layout, k = 78*(k'/CW) + k'%CW, valid (k'%CW)<78
template <int CW>
__global__ __launch_bounds__(256) void wt_conv(const float* __restrict__ W, _Float16* __restrict__ WT,
                                               int K, int Nout, int ldw, int KP, int total) {
  int i = blockIdx.x * 256 + threadIdx.x;
  if (i >= total) return;
  int c = i / KP, kp = i - c * KP;
  int k; bool valid;
  if (CW) { int blk = kp / CW, r = kp - blk * CW; k = blk * 78 + r; valid = (r < 78) && (k < K); }
  else { k = kp; valid = kp < K; }
  WT[i] = (valid && c < Nout) ? (_Float16)W[(size_t)k * ldw + c] : (_Float16)0.f;
}

// Xh[n, 0:96] = f16(x[n, 0:78]), zero pad
__global__ __launch_bounds__(256) void xconv(const float* __restrict__ xin, _Float16* __restrict__ Xh) {
  unsigned idx = blockIdx.x * 256u + threadIdx.x;
  if (idx >= (unsigned)N_NODES * 48u) return;
  unsigned n = idx / 48u, c2 = idx - n * 48u;
  __half2 h = __floats2half2_rn(0.f, 0.f);
  if (c2 < 39u) {
    float2 v = *reinterpret_cast<const float2*>(xin + (size_t)n * 78 + 2 * c2);
    h = __floats2half2_rn(v.x, v.y);
  }
  *reinterpret_cast<__half2*>((__half*)Xh + (size_t)n * 96 + 2 * c2) = h;
}

// Direct-register MFMA GEMM. in [M,KP] f16; WT [*,KP] f16 pre-transposed. Tile 128x80.
// BLDS=1: stage B in LDS fragment-linear (conflict-free), single barrier.
// PLANE=1: blockIdx.x = output chunk; out16 += x*planeStride (col offset), WT += x*78*KP.
// NS<=5: A-fragment loads explicitly hoisted into register arrays BEFORE the MFMA
// chain -> 2*NS independent 1KB global loads in flight per wave (fixes the
// VGPR=52 serialization seen in r12: only ~2 loads in flight, 30us/block stall).
// OUT_MODE 0: v*rs[row] -> f16 ; 1: relu(v+bo) -> f16 ; 2: v+bo -> f32
template <int KP, int OUT_MODE, int BLDS, int PLANE>
__global__ __launch_bounds__(256) void gemm_direct(
    const _Float16* __restrict__ in, const _Float16* __restrict__ WT,
    void* __restrict__ outp, const float* __restrict__ rs, const float* __restrict__ bo,
    int M, int Nout, int LDO, size_t planeStride) {
  constexpr int NS = KP / 32;
  constexpr bool HOIST = (NS <= 5);
  __shared__ _Float16 Bs[BLDS ? 5 * NS * 64 * 8 : 8];
  const int tid = threadIdx.x;
  const int lane = tid & 63;
  const int wid = tid >> 6;
  const int row0 = blockIdx.y * 128;
  const int col0 = PLANE ? 0 : blockIdx.x * 80;
  const _Float16* wt = WT + (size_t)(PLANE ? blockIdx.x * 78 : col0) * KP;
  _Float16* out16 = (_Float16*)outp + (PLANE ? (size_t)blockIdx.x * planeStride : 0);
  float* out32 = (float*)outp;
  const int koff = (lane >> 4) * 8;
  const int gr0 = row0 + wid * 32 + (lane & 15);
  const bool v0 = gr0 < M, v1 = (gr0 + 16) < M;
  const _Float16* a0 = in + (size_t)gr0 * KP + koff;
  const _Float16* a1 = a0 + (size_t)16 * KP;
  const _Float16* bp = wt + (size_t)(lane & 15) * KP + koff;

  if (BLDS) {
    for (int i = tid; i < 5 * NS * 64; i += 256) {
      int l = i & 63;
      int nf = (i >> 6) % 5;
      int s = i / 320;
      int r = nf * 16 + (l & 15);
      int k = s * 32 + ((l >> 4) << 3);
      *reinterpret_cast<uint4*>(&Bs[(size_t)i * 8]) =
          *reinterpret_cast<const uint4*>(wt + (size_t)r * KP + k);
    }
    __syncthreads();
  }

  const f16x8 zf = {0, 0, 0, 0, 0, 0, 0, 0};
  const f32x4 z4 = {0.f, 0.f, 0.f, 0.f};
  f32x4 acc[2][5];
#pragma unroll
  for (int a = 0; a < 2; ++a)
#pragma unroll
    for (int b = 0; b < 5; ++b) acc[a][b] = z4;

  if constexpr (HOIST) {
    f16x8 A0[NS], A1[NS];
#pragma unroll
    for (int s = 0; s < NS; ++s) {
      A0[s] = v0 ? *reinterpret_cast<const f16x8*>(a0 + s * 32) : zf;
      A1[s] = v1 ? *reinterpret_cast<const f16x8*>(a1 + s * 32) : zf;
    }
#pragma unroll
    for (int s = 0; s < NS; ++s) {
      f16x8 bf[5];
#pragma unroll
      for (int nf = 0; nf < 5; ++nf) {
        if (BLDS)
          bf[nf] = *reinterpret_cast<const f16x8*>(&Bs[((size_t)(s * 5 + nf) * 64 + lane) * 8]);
        else
          bf[nf] = *reinterpret_cast<const f16x8*>(bp + (size_t)nf * 16 * KP + s * 32);
      }
#pragma unroll
      for (int nf = 0; nf < 5; ++nf) {
        acc[0][nf] = __builtin_amdgcn_mfma_f32_16x16x32_f16(A0[s], bf[nf], acc[0][nf], 0, 0, 0);
        acc[1][nf] = __builtin_amdgcn_mfma_f32_16x16x32_f16(A1[s], bf[nf], acc[1][nf], 0, 0, 0);
      }
    }
  } else {
#pragma unroll
    for (int s = 0; s < NS; ++s) {
      f16x8 af0 = v0 ? *reinterpret_cast<const f16x8*>(a0 + s * 32) : zf;
      f16x8 af1 = v1 ? *reinterpret_cast<const f16x8*>(a1 + s * 32) : zf;
      f16x8 bf[5];
#pragma unroll
      for (int nf = 0; nf < 5; ++nf) {
        if (BLDS)
          bf[nf] = *reinterpret_cast<const f16x8*>(&Bs[((size_t)(s * 5 + nf) * 64 + lane) * 8]);
        else
          bf[nf] = *reinterpret_cast<const f16x8*>(bp + (size_t)nf * 16 * KP + s * 32);
      }
#pragma unroll
      for (int nf = 0; nf < 5; ++nf) {
        acc[0][nf] = __builtin_amdgcn_mfma_f32_16x16x32_f16(af0, bf[nf], acc[0][nf], 0, 0, 0);
        acc[1][nf] = __builtin_amdgcn_mfma_f32_16x16x32_f16(af1, bf[nf], acc[1][nf], 0, 0, 0);
      }
    }
  }

  // epilogue: C/D col=lane&15, row=(lane>>4)*4+reg
#pragma unroll
  for (int rf = 0; rf < 2; ++rf) {
#pragma unroll
    for (int j = 0; j < 4; ++j) {
      int gr = row0 + wid * 32 + rf * 16 + (lane >> 4) * 4 + j;
      if (gr >= M) continue;
      float sc = (OUT_MODE == 0) ? rs[gr] : 0.f;
#pragma unroll
      for (int nf = 0; nf < 5; ++nf) {
        int oc = col0 + nf * 16 + (lane & 15);
        if (oc >= Nout) continue;
        float v = acc[rf][nf][j];
        if (OUT_MODE == 0) {
          out16[(size_t)gr * LDO + oc] = (_Float16)(v * sc);
        } else if (OUT_MODE == 1) {
          out16[(size_t)gr * LDO + oc] = (_Float16)fmaxf(v + bo[oc], 0.f);
        } else {
          out32[(size_t)gr * LDO + oc] = v + bo[oc];
        }
      }
    }
  }
}

__device__ inline void acc8(float* a, uint4 v) {
  const __half2* h = reinterpret_cast<const __half2*>(&v);
#pragma unroll
  for (int j = 0; j < 4; ++j) {
    float2 f = __half22float2(h[j]);
    a[2 * j] += f.x;
    a[2 * j + 1] += f.y;
  }
}

// segment-sum gather; hs rows have stride 160 f16 from hbase
__device__ inline void gather_sum(float* a, const _Float16* hbase, unsigned n,
                                  const int4* __restrict__ ell,
                                  const int* __restrict__ rowptr,
                                  const int* __restrict__ ssrc) {
  int4 e = ell[n];
  const int deg = e.x;
  uint4 sv = *reinterpret_cast<const uint4*>(hbase + (size_t)n * 160);
  uint4 g0, g1, g2;
  if (deg > 0) g0 = *reinterpret_cast<const uint4*>(hbase + (size_t)e.y * 160);
  if (deg > 1) g1 = *reinterpret_cast<const uint4*>(hbase + (size_t)e.z * 160);
  if (deg > 2) g2 = *reinterpret_cast<const uint4*>(hbase + (size_t)e.w * 160);
  {
    const __half2* h = reinterpret_cast<const __half2*>(&sv);
#pragma unroll
    for (int j = 0; j < 4; ++j) {
      float2 f = __half22float2(h[j]);
      a[2 * j] = f.x;
      a[2 * j + 1] = f.y;
    }
  }
  if (deg > 0) acc8(a, g0);
  if (deg > 1) acc8(a, g1);
  if (deg > 2) acc8(a, g2);
  if (deg > 3) {
    int r = rowptr[n] + 3, r1 = r + deg - 3;
    for (; r + 2 <= r1; r += 2) {
      uint4 va = *reinterpret_cast<const uint4*>(hbase + (size_t)ssrc[r] * 160);
      uint4 vb = *reinterpret_cast<const uint4*>(hbase + (size_t)ssrc[r + 1] * 160);
      acc8(a, va);
      acc8(a, vb);
    }
    if (r < r1) {
      uint4 va = *reinterpret_cast<const uint4*>(hbase + (size_t)ssrc[r] * 160);
      acc8(a, va);
    }
  }
}

// Fused segment-sum + transform over NCHUNK 80-wide chunks of hs [N,160].
// Thread (n, c, sub): reads hs[n, rcoff + c*80 + sub*8 ..+8], writes
// dsth[n*ldo + c*ocs + sub*8] = relu(dinv*(self+gather) + b[boff + c*78 + f]), pad f>=78 -> bias 0.
template <int NCHUNK>
__global__ __launch_bounds__(256) void aggregateN(
    const _Float16* __restrict__ hs, const int4* __restrict__ ell,
    const int* __restrict__ rowptr, const int* __restrict__ ssrc,
    const float* __restrict__ dinv, const float* __restrict__ b,
    _Float16* __restrict__ dsth, int ldo, int ocs, int boff, int rcoff) {
  constexpr unsigned T = NCHUNK * 10;
  unsigned idx = blockIdx.x * 256u + threadIdx.x;
  if (idx >= (unsigned)N_NODES * T) return;
  unsigned n = idx / T, q = idx - n * T;
  unsigned c = q / 10, sub = q - c * 10;
  float a[8];
  gather_sum(a, hs + rcoff + c * 80 + sub * 8, n, ell, rowptr, ssrc);
  float di = dinv[n];
  _Float16 ov[8];
#pragma unroll
  for (int j = 0; j < 8; ++j) {
    int f = sub * 8 + j;
    float bv = (f < 78) ? b[boff + c * 78 + f] : 0.f;
    ov[j] = (_Float16)fmaxf(fmaf(di, a[j], bv), 0.f);
  }
  *reinterpret_cast<uint4*>(dsth + (size_t)n * ldo + c * ocs + sub * 8) =
      *reinterpret_cast<const uint4*>(ov);
}

// Mean-pool over contiguous node range, 16B/thread (10 threads/graph):
// GA[g*320 + coffGA + q*8..] = (1/cnt) Σ_n TR[n*80 + q*8..]
__global__ __launch_bounds__(256) void pool_seq(
    const _Float16* __restrict__ TR, const int* __restrict__ gstart,
    _Float16* __restrict__ GA, int coffGA) {
  unsigned idx = blockIdx.x * 256u + threadIdx.x;
  if (idx >= (unsigned)N_GRAPHS * 10u) return;
  unsigned g = idx / 10u, q = idx - g * 10u;
  int n0 = gstart[g], n1 = gstart[g + 1];
  const _Float16* base = TR + q * 8;
  float a[8] = {0.f, 0.f, 0.f, 0.f, 0.f, 0.f, 0.f, 0.f};
  float b2[8] = {0.f, 0.f, 0.f, 0.f, 0.f, 0.f, 0.f, 0.f};
  int n = n0;
  for (; n + 2 <= n1; n += 2) {
    uint4 va = *reinterpret_cast<const uint4*>(base + (size_t)n * 80);
    uint4 vb = *reinterpret_cast<const uint4*>(base + (size_t)(n + 1) * 80);
    acc8(a, va);
    acc8(b2, vb);
  }
  if (n < n1) {
    uint4 va = *reinterpret_cast<const uint4*>(base + (size_t)n * 80);
    acc8(a, va);
  }
  float gi = 1.0f / fmaxf((float)(n1 - n0), 1.0f);
  _Float16 ov[8];
#pragma unroll
  for (int j = 0; j < 8; ++j) ov[j] = (_Float16)((a[j] + b2[j]) * gi);
  *reinterpret_cast<uint4*>(GA + (size_t)g * 320 + coffGA + q * 8) =
      *reinterpret_cast<const uint4*>(ov);
}

extern "C" void kernel_launch(void* const* d_in, const int* in_sizes, int n_in,
                              void* d_out, int out_size, void* d_ws, size_t ws_size,
                              hipStream_t stream) {
  const float* x   = (const float*)d_in[0];
  const int* ei    = (const int*)d_in[1];
  const int* batch = (const int*)d_in[2];
  const float* W1 = (const float*)d_in[3];
  const float* b1 = (const float*)d_in[4];
  const float* W2 = (const float*)d_in[5];
  const float* b2 = (const float*)d_in[6];
  const float* W3 = (const float*)d_in[7];
  const float* b3 = (const float*)d_in[8];
  const float* fW1 = (const float*)d_in[9];
  const float* fb1 = (const float*)d_in[10];
  const float* fW2 = (const float*)d_in[11];
  const float* fb2 = (const float*)d_in[12];
  float* out = (float*)d_out;

  const int Nn = N_NODES, E = N_EDGES, G = N_GRAPHS;
  const int* src = ei;
  const int* dst = ei + E;

  // ---- workspace layout (~450 MB) ----
  _Float16* AGG2h = (_Float16*)d_ws;                      // [N,160]
  _Float16* Xh    = AGG2h;                                // [N,96]
  _Float16* AGG1h = AGG2h + (size_t)Nn * 160;             // [N,96]
  _Float16* TR    = AGG1h;                                // [N,80] (L3)
  _Float16* HS2   = AGG1h + (size_t)Nn * 96;              // [N,160]
  _Float16* fc1   = HS2;                                  // [G,1056] (after L3)
  _Float16* GA    = HS2 + (size_t)Nn * 160;               // [G,320] chunk80
  _Float16* W1T   = GA + (size_t)G * 320;                 // [80][96]
  _Float16* W2T   = W1T + 80 * 96;                        // [160][96]
  _Float16* W3T   = W2T + 160 * 96;                       // [320][160] chunk80
  _Float16* fW1T  = W3T + 320 * 160;                      // [1040][320] chunk80
  _Float16* fW2T  = fW1T + (size_t)1040 * 320;            // [160][1056]
  float* dinv     = (float*)(fW2T + (size_t)160 * 1056);  // [N]
  int* rowptr     = (int*)(dinv + Nn);                    // [N+1]
  int* cur        = rowptr + Nn + 1;                      // [N]
  int* ssrc       = cur + Nn;                             // [E]
  int* partials   = ssrc + E;                             // [512]
  int* gstart     = partials + 512;                       // [G+1]
  int4* ell = (int4*)(((uintptr_t)(gstart + G + 1) + 15) & ~(uintptr_t)15);  // [N]

  dim3 blk(256);
  const int gN10 = (int)(((unsigned)Nn * 10u + 255u) / 256u);
  const int gN20 = (int)(((unsigned)Nn * 20u + 255u) / 256u);
  const int gG10 = (int)(((unsigned)G * 10u + 255u) / 256u);
  const dim3 nodeGrid(1, (Nn + 127) / 128);
  const dim3 pairGrid(2, (Nn + 127) / 128);
  const int NB = (Nn + 1023) / 1024;  // 489

  // ---- CSR build + ELL + graph starts ----
  fill_u32<<<(Nn + 255) / 256, blk, 0, stream>>>((unsigned*)cur, 0u, Nn);
  hist_dst<<<(E + 255) / 256, blk, 0, stream>>>(dst, cur, E);
  scanA<<<NB, blk, 0, stream>>>(cur, rowptr, partials, Nn);
  scanB<<<1, 512, 0, stream>>>(partials, NB);
  scanC<<<(Nn + 255) / 256, blk, 0, stream>>>(rowptr, partials, cur, Nn, E);
  dinv_k<<<(Nn + 255) / 256, blk, 0, stream>>>(rowptr, dinv, Nn);
  bucket<<<(E + 255) / 256, blk, 0, stream>>>(src, dst, cur, ssrc, E);
  ell_build<<<(Nn + 255) / 256, blk, 0, stream>>>(rowptr, ssrc, ell, Nn);
  graph_starts<<<(Nn + 256) / 256, blk, 0, stream>>>(batch, gstart, Nn);

  // ---- fp16 transposed weights ----
  wt_conv<0><<<(80 * 96 + 255) / 256, blk, 0, stream>>>(W1, W1T, 78, 78, 78, 96, 80 * 96);
  wt_conv<0><<<(160 * 96 + 255) / 256, blk, 0, stream>>>(W2, W2T, 78, 156, 156, 96, 160 * 96);
  wt_conv<80><<<(320 * 160 + 255) / 256, blk, 0, stream>>>(W3, W3T, 156, 312, 312, 160, 320 * 160);
  wt_conv<80><<<(1040 * 320 + 255) / 256, blk, 0, stream>>>(fW1, fW1T, 312, 1024, 1024, 320, 1040 * 320);
  wt_conv<0><<<(160 * 1056 + 255) / 256, blk, 0, stream>>>(fW2, fW2T, 1024, 128, 128, 1056, 160 * 1056);

  // ---- x -> f16 [N,96] ----
  xconv<<<(int)(((unsigned)Nn * 48u + 255u) / 256u), blk, 0, stream>>>(x, Xh);

  // ---- layer 1: gemm -> HS2 plane0 ; aggregate (1 chunk) -> AGG1h ----
  gemm_direct<96, 0, 1, 0><<<nodeGrid, blk, 0, stream>>>(Xh, W1T, HS2, dinv, nullptr, Nn, 78, 160, 0);
  aggregateN<1><<<gN10, blk, 0, stream>>>(HS2, ell, rowptr, ssrc, dinv, b1, AGG1h, 96, 96, 0, 0);

  // ---- layer 2: merged plane-pair gemm -> HS2[2][80] ; 1 aggregate (2 chunks) -> AGG2h ----
  gemm_direct<96, 0, 1, 1><<<pairGrid, blk, 0, stream>>>(AGG1h, W2T, HS2, dinv, nullptr, Nn, 78, 160, 80);
  aggregateN<2><<<gN20, blk, 0, stream>>>(HS2, ell, rowptr, ssrc, dinv, b2, AGG2h, 160, 80, 0, 0);

  // ---- layer 3: 2 passes x {plane-pair gemm; per-chunk aggregate -> TR -> pool} ----
  for (int p = 0; p < 2; ++p) {
    gemm_direct<160, 0, 1, 1><<<pairGrid, blk, 0, stream>>>(
        AGG2h, W3T + (size_t)(156 * p) * 160, HS2, dinv, nullptr, Nn, 78, 160, 80);
    for (int cc = 0; cc < 2; ++cc) {
      aggregateN<1><<<gN10, blk, 0, stream>>>(HS2, ell, rowptr, ssrc, dinv, b3, TR,
                                              80, 80, 156 * p + 78 * cc, 80 * cc);
      pool_seq<<<gG10, blk, 0, stream>>>(TR, gstart, GA, (2 * p + cc) * 80);
    }
  }

  // ---- FC1: relu(GA @ fW1 + fb1) -> fc1 f16 (B staged in 50 KB LDS) ----
  {
    dim3 g((1024 + 79) / 80, (G + 127) / 128);  // 13 x 157
    gemm_direct<320, 1, 1, 0><<<g, blk, 0, stream>>>(GA, fW1T, fc1, nullptr, fb1, G, 1024, 1056, 0);
  }
  // ---- FC2: out = fc1 @ fW2 + fb2 (f32) ----
  {
    dim3 g((128 + 79) / 80, (G + 127) / 128);  // 2 x 157
    gemm_direct<1056, 2, 0, 0><<<g, blk, 0, stream>>>(fc1, fW2T, out, nullptr, fb2, G, 128, 128, 0);
  }
}

// Round 14
// 1092.943 us; speedup vs baseline: 1.8553x; 1.2587x over previous
//
#include <hip/hip_runtime.h>
#include <hip/hip_fp16.h>

#define N_NODES 500000
#define N_EDGES 1000000
#define N_GRAPHS 20000

typedef _Float16 f16x8 __attribute__((ext_vector_type(8)));
typedef float f32x4 __attribute__((ext_vector_type(4)));

__global__ __launch_bounds__(256) void fill_u32(unsigned* p, unsigned v, int n) {
  int i = blockIdx.x * 256 + threadIdx.x;
  if (i < n) p[i] = v;
}

__global__ __launch_bounds__(256) void hist_dst(const int* __restrict__ dst, int* cnt, int e) {
  int i = blockIdx.x * 256 + threadIdx.x;
  if (i < e) atomicAdd(&cnt[dst[i]], 1);
}

// ---- 2-level exclusive scan over deg[N] (1024 elems/block) ----
__global__ __launch_bounds__(256) void scanA(const int* __restrict__ deg, int* __restrict__ loc,
                                             int* __restrict__ partials, int n) {
  __shared__ int ts[256];
  int b = blockIdx.x, t = threadIdx.x;
  int base = b * 1024 + t * 4;
  int v[4], s = 0;
#pragma unroll
  for (int j = 0; j < 4; ++j) {
    v[j] = (base + j < n) ? deg[base + j] : 0;
    s += v[j];
  }
  ts[t] = s;
  __syncthreads();
  for (int off = 1; off < 256; off <<= 1) {
    int x = (t >= off) ? ts[t - off] : 0;
    __syncthreads();
    ts[t] += x;
    __syncthreads();
  }
  if (t == 255) partials[b] = ts[255];
  int run = ts[t] - s;  // exclusive
#pragma unroll
  for (int j = 0; j < 4; ++j) {
    if (base + j < n) loc[base + j] = run;
    run += v[j];
  }
}

__global__ __launch_bounds__(512) void scanB(int* partials, int nb) {
  __shared__ int s[512];
  int t = threadIdx.x;
  s[t] = (t < nb) ? partials[t] : 0;
  __syncthreads();
  if (t == 0) {
    int run = 0;
    for (int i = 0; i < nb; ++i) { int v = s[i]; s[i] = run; run += v; }
  }
  __syncthreads();
  if (t < nb) partials[t] = s[t];
}

__global__ __launch_bounds__(256) void scanC(int* __restrict__ rowptr, const int* __restrict__ partials,
                                             int* __restrict__ cur, int n, int e) {
  int i = blockIdx.x * 256 + threadIdx.x;
  if (i < n) {
    int v = rowptr[i] + partials[i >> 10];
    rowptr[i] = v;
    cur[i] = v;
  }
  if (i == 0) rowptr[n] = e;
}

__global__ __launch_bounds__(256) void dinv_k(const int* __restrict__ rowptr, float* dinv, int n) {
  int i = blockIdx.x * 256 + threadIdx.x;
  if (i < n) dinv[i] = rsqrtf(1.0f + (float)(rowptr[i + 1] - rowptr[i]));
}

__global__ __launch_bounds__(256) void bucket(const int* __restrict__ src, const int* __restrict__ dst,
                                              int* __restrict__ cur, int* __restrict__ ssrc, int e) {
  int i = blockIdx.x * 256 + threadIdx.x;
  if (i < e) ssrc[atomicAdd(&cur[dst[i]], 1)] = src[i];
}

// ell[n] = {deg, s0, s1, s2}
__global__ __launch_bounds__(256) void ell_build(const int* __restrict__ rowptr,
                                                 const int* __restrict__ ssrc,
                                                 int4* __restrict__ ell, int n) {
  int i = blockIdx.x * 256 + threadIdx.x;
  if (i >= n) return;
  int r0 = rowptr[i], r1 = rowptr[i + 1];
  int deg = r1 - r0;
  int4 e;
  e.x = deg;
  e.y = (deg > 0) ? ssrc[r0] : 0;
  e.z = (deg > 1) ? ssrc[r0 + 1] : 0;
  e.w = (deg > 2) ? ssrc[r0 + 2] : 0;
  ell[i] = e;
}

// gstart[g] = first node index of graph g (batch sorted); gstart[G] = N
__global__ __launch_bounds__(256) void graph_starts(const int* __restrict__ batch,
                                                    int* __restrict__ gstart, int n) {
  int i = blockIdx.x * 256 + threadIdx.x;
  if (i < n) {
    int b = batch[i];
    int bp = (i == 0) ? -1 : batch[i - 1];
    for (int g = bp + 1; g <= b; ++g) gstart[g] = i;
  } else if (i == n) {
    int bl = batch[n - 1];
    for (int g = bl + 1; g <= N_GRAPHS; ++g) gstart[g] = n;
  }
}

// WT[c][k'] = f16(W[k][c]); CW>0: chunk layout, k = 78*(k'/CW) + k'%CW, valid (k'%CW)<78
template <int CW>
__global__ __launch_bounds__(256) void wt_conv(const float* __restrict__ W, _Float16* __restrict__ WT,
                                               int K, int Nout, int ldw, int KP, int total) {
  int i = blockIdx.x * 256 + threadIdx.x;
  if (i >= total) return;
  int c = i / KP, kp = i - c * KP;
  int k; bool valid;
  if (CW) { int blk = kp / CW, r = kp - blk * CW; k = blk * 78 + r; valid = (r < 78) && (k < K); }
  else { k = kp; valid = kp < K; }
  WT[i] = (valid && c < Nout) ? (_Float16)W[(size_t)k * ldw + c] : (_Float16)0.f;
}

// Xh[n, 0:96] = f16(x[n, 0:78] * dinv[n]), zero pad (pre-scaled activations X' = D X)
__global__ __launch_bounds__(256) void xconv(const float* __restrict__ xin,
                                             const float* __restrict__ dinv,
                                             _Float16* __restrict__ Xh) {
  unsigned idx = blockIdx.x * 256u + threadIdx.x;
  if (idx >= (unsigned)N_NODES * 48u) return;
  unsigned n = idx / 48u, c2 = idx - n * 48u;
  __half2 h = __floats2half2_rn(0.f, 0.f);
  if (c2 < 39u) {
    float di = dinv[n];
    float2 v = *reinterpret_cast<const float2*>(xin + (size_t)n * 78 + 2 * c2);
    h = __floats2half2_rn(v.x * di, v.y * di);
  }
  *reinterpret_cast<__half2*>((__half*)Xh + (size_t)n * 96 + 2 * c2) = h;
}

// Direct-register MFMA GEMM. in [M,KP] f16; WT [*,KP] f16 pre-transposed. Tile 128x80.
// BLDS=1: stage B in LDS fragment-linear (conflict-free), single barrier.
// PLANE=1: blockIdx.x = output chunk; out16 += x*planeStride, WT += x*78*KP, bias += x*78.
// NS<=5: A-fragments hoisted to registers before MFMA chain (MLP fix, r13).
// OUT_MODE 1: relu(v+b) -> f16 ; 2: v+b -> f32 ; 3: relu(v+b)*rs[row] -> f16
template <int KP, int OUT_MODE, int BLDS, int PLANE>
__global__ __launch_bounds__(256) void gemm_direct(
    const _Float16* __restrict__ in, const _Float16* __restrict__ WT,
    void* __restrict__ outp, const float* __restrict__ rs, const float* __restrict__ bo,
    int M, int Nout, int LDO, size_t planeStride) {
  constexpr int NS = KP / 32;
  constexpr bool HOIST = (NS <= 5);
  __shared__ _Float16 Bs[BLDS ? 5 * NS * 64 * 8 : 8];
  const int tid = threadIdx.x;
  const int lane = tid & 63;
  const int wid = tid >> 6;
  const int row0 = blockIdx.y * 128;
  const int col0 = PLANE ? 0 : blockIdx.x * 80;
  const _Float16* wt = WT + (size_t)(PLANE ? blockIdx.x * 78 : col0) * KP;
  const float* bop = PLANE ? bo + blockIdx.x * 78 : bo;
  _Float16* out16 = (_Float16*)outp + (PLANE ? (size_t)blockIdx.x * planeStride : 0);
  float* out32 = (float*)outp;
  const int koff = (lane >> 4) * 8;
  const int gr0 = row0 + wid * 32 + (lane & 15);
  const bool v0 = gr0 < M, v1 = (gr0 + 16) < M;
  const _Float16* a0 = in + (size_t)gr0 * KP + koff;
  const _Float16* a1 = a0 + (size_t)16 * KP;
  const _Float16* bp = wt + (size_t)(lane & 15) * KP + koff;

  if (BLDS) {
    for (int i = tid; i < 5 * NS * 64; i += 256) {
      int l = i & 63;
      int nf = (i >> 6) % 5;
      int s = i / 320;
      int r = nf * 16 + (l & 15);
      int k = s * 32 + ((l >> 4) << 3);
      *reinterpret_cast<uint4*>(&Bs[(size_t)i * 8]) =
          *reinterpret_cast<const uint4*>(wt + (size_t)r * KP + k);
    }
    __syncthreads();
  }

  const f16x8 zf = {0, 0, 0, 0, 0, 0, 0, 0};
  const f32x4 z4 = {0.f, 0.f, 0.f, 0.f};
  f32x4 acc[2][5];
#pragma unroll
  for (int a = 0; a < 2; ++a)
#pragma unroll
    for (int b = 0; b < 5; ++b) acc[a][b] = z4;

  if constexpr (HOIST) {
    f16x8 A0[NS], A1[NS];
#pragma unroll
    for (int s = 0; s < NS; ++s) {
      A0[s] = v0 ? *reinterpret_cast<const f16x8*>(a0 + s * 32) : zf;
      A1[s] = v1 ? *reinterpret_cast<const f16x8*>(a1 + s * 32) : zf;
    }
#pragma unroll
    for (int s = 0; s < NS; ++s) {
      f16x8 bf[5];
#pragma unroll
      for (int nf = 0; nf < 5; ++nf) {
        if (BLDS)
          bf[nf] = *reinterpret_cast<const f16x8*>(&Bs[((size_t)(s * 5 + nf) * 64 + lane) * 8]);
        else
          bf[nf] = *reinterpret_cast<const f16x8*>(bp + (size_t)nf * 16 * KP + s * 32);
      }
#pragma unroll
      for (int nf = 0; nf < 5; ++nf) {
        acc[0][nf] = __builtin_amdgcn_mfma_f32_16x16x32_f16(A0[s], bf[nf], acc[0][nf], 0, 0, 0);
        acc[1][nf] = __builtin_amdgcn_mfma_f32_16x16x32_f16(A1[s], bf[nf], acc[1][nf], 0, 0, 0);
      }
    }
  } else {
#pragma unroll
    for (int s = 0; s < NS; ++s) {
      f16x8 af0 = v0 ? *reinterpret_cast<const f16x8*>(a0 + s * 32) : zf;
      f16x8 af1 = v1 ? *reinterpret_cast<const f16x8*>(a1 + s * 32) : zf;
      f16x8 bf[5];
#pragma unroll
      for (int nf = 0; nf < 5; ++nf) {
        if (BLDS)
          bf[nf] = *reinterpret_cast<const f16x8*>(&Bs[((size_t)(s * 5 + nf) * 64 + lane) * 8]);
        else
          bf[nf] = *reinterpret_cast<const f16x8*>(bp + (size_t)nf * 16 * KP + s * 32);
      }
#pragma unroll
      for (int nf = 0; nf < 5; ++nf) {
        acc[0][nf] = __builtin_amdgcn_mfma_f32_16x16x32_f16(af0, bf[nf], acc[0][nf], 0, 0, 0);
        acc[1][nf] = __builtin_amdgcn_mfma_f32_16x16x32_f16(af1, bf[nf], acc[1][nf], 0, 0, 0);
      }
    }
  }

  // epilogue: C/D col=lane&15, row=(lane>>4)*4+reg
#pragma unroll
  for (int rf = 0; rf < 2; ++rf) {
#pragma unroll
    for (int j = 0; j < 4; ++j) {
      int gr = row0 + wid * 32 + rf * 16 + (lane >> 4) * 4 + j;
      if (gr >= M) continue;
      float sc = (OUT_MODE == 3) ? rs[gr] : 0.f;
#pragma unroll
      for (int nf = 0; nf < 5; ++nf) {
        int oc = col0 + nf * 16 + (lane & 15);
        if (oc >= Nout) continue;
        float v = acc[rf][nf][j];
        if (OUT_MODE == 1) {
          out16[(size_t)gr * LDO + oc] = (_Float16)fmaxf(v + bop[oc], 0.f);
        } else if (OUT_MODE == 3) {
          out16[(size_t)gr * LDO + oc] = (_Float16)(fmaxf(v + bop[oc], 0.f) * sc);
        } else {
          out32[(size_t)gr * LDO + oc] = v + bop[oc];
        }
      }
    }
  }
}

__device__ inline void acc8(float* a, uint4 v) {
  const __half2* h = reinterpret_cast<const __half2*>(&v);
#pragma unroll
  for (int j = 0; j < 4; ++j) {
    float2 f = __half22float2(h[j]);
    a[2 * j] += f.x;
    a[2 * j + 1] += f.y;
  }
}

// segment-sum gather; hs rows have stride LDI f16 from hbase
template <int LDI>
__device__ inline void gather_sumT(float* a, const _Float16* hbase, unsigned n,
                                   const int4* __restrict__ ell,
                                   const int* __restrict__ rowptr,
                                   const int* __restrict__ ssrc) {
  int4 e = ell[n];
  const int deg = e.x;
  uint4 sv = *reinterpret_cast<const uint4*>(hbase + (size_t)n * LDI);
  uint4 g0, g1, g2;
  if (deg > 0) g0 = *reinterpret_cast<const uint4*>(hbase + (size_t)e.y * LDI);
  if (deg > 1) g1 = *reinterpret_cast<const uint4*>(hbase + (size_t)e.z * LDI);
  if (deg > 2) g2 = *reinterpret_cast<const uint4*>(hbase + (size_t)e.w * LDI);
  {
    const __half2* h = reinterpret_cast<const __half2*>(&sv);
#pragma unroll
    for (int j = 0; j < 4; ++j) {
      float2 f = __half22float2(h[j]);
      a[2 * j] = f.x;
      a[2 * j + 1] = f.y;
    }
  }
  if (deg > 0) acc8(a, g0);
  if (deg > 1) acc8(a, g1);
  if (deg > 2) acc8(a, g2);
  if (deg > 3) {
    int r = rowptr[n] + 3, r1 = r + deg - 3;
    for (; r + 2 <= r1; r += 2) {
      uint4 va = *reinterpret_cast<const uint4*>(hbase + (size_t)ssrc[r] * LDI);
      uint4 vb = *reinterpret_cast<const uint4*>(hbase + (size_t)ssrc[r + 1] * LDI);
      acc8(a, va);
      acc8(a, vb);
    }
    if (r < r1) {
      uint4 va = *reinterpret_cast<const uint4*>(hbase + (size_t)ssrc[r] * LDI);
      acc8(a, va);
    }
  }
}

// Input-side aggregation: Z[n] = f16(dinv[n] * (in[n] + Σ_seg in[ssrc]))
// (activations pre-scaled by dinv, so this computes D(I+Adj)D X exactly).
// Thread (n, sub): 16B chunk sub of row n; NSUB chunks cover the aggregated width.
template <int LDI, int NSUB>
__global__ __launch_bounds__(256) void aggregateZ(
    const _Float16* __restrict__ in, const int4* __restrict__ ell,
    const int* __restrict__ rowptr, const int* __restrict__ ssrc,
    const float* __restrict__ dinv, _Float16* __restrict__ outZ, int ldo) {
  unsigned idx = blockIdx.x * 256u + threadIdx.x;
  if (idx >= (unsigned)N_NODES * NSUB) return;
  unsigned n = idx / NSUB, sub = idx - n * NSUB;
  float a[8];
  gather_sumT<LDI>(a, in + sub * 8u, n, ell, rowptr, ssrc);
  float di = dinv[n];
  _Float16 ov[8];
#pragma unroll
  for (int j = 0; j < 8; ++j) ov[j] = (_Float16)(di * a[j]);
  *reinterpret_cast<uint4*>(outZ + (size_t)n * ldo + sub * 8u) =
      *reinterpret_cast<const uint4*>(ov);
}

// Mean-pool over contiguous node range, 16B/thread (10 threads/graph):
// GA[g*320 + coffGA + q*8..] = (1/cnt) Σ_n in[n*160 + inOff + q*8..]
__global__ __launch_bounds__(256) void pool_seq(
    const _Float16* __restrict__ in, const int* __restrict__ gstart,
    _Float16* __restrict__ GA, int inOff, int coffGA) {
  unsigned idx = blockIdx.x * 256u + threadIdx.x;
  if (idx >= (unsigned)N_GRAPHS * 10u) return;
  unsigned g = idx / 10u, q = idx - g * 10u;
  int n0 = gstart[g], n1 = gstart[g + 1];
  const _Float16* base = in + inOff + q * 8;
  float a[8] = {0.f, 0.f, 0.f, 0.f, 0.f, 0.f, 0.f, 0.f};
  float b2[8] = {0.f, 0.f, 0.f, 0.f, 0.f, 0.f, 0.f, 0.f};
  int n = n0;
  for (; n + 2 <= n1; n += 2) {
    uint4 va = *reinterpret_cast<const uint4*>(base + (size_t)n * 160);
    uint4 vb = *reinterpret_cast<const uint4*>(base + (size_t)(n + 1) * 160);
    acc8(a, va);
    acc8(b2, vb);
  }
  if (n < n1) {
    uint4 va = *reinterpret_cast<const uint4*>(base + (size_t)n * 160);
    acc8(a, va);
  }
  float gi = 1.0f / fmaxf((float)(n1 - n0), 1.0f);
  _Float16 ov[8];
#pragma unroll
  for (int j = 0; j < 8; ++j) ov[j] = (_Float16)((a[j] + b2[j]) * gi);
  *reinterpret_cast<uint4*>(GA + (size_t)g * 320 + coffGA + q * 8) =
      *reinterpret_cast<const uint4*>(ov);
}

extern "C" void kernel_launch(void* const* d_in, const int* in_sizes, int n_in,
                              void* d_out, int out_size, void* d_ws, size_t ws_size,
                              hipStream_t stream) {
  const float* x   = (const float*)d_in[0];
  const int* ei    = (const int*)d_in[1];
  const int* batch = (const int*)d_in[2];
  const float* W1 = (const float*)d_in[3];
  const float* b1 = (const float*)d_in[4];
  const float* W2 = (const float*)d_in[5];
  const float* b2 = (const float*)d_in[6];
  const float* W3 = (const float*)d_in[7];
  const float* b3 = (const float*)d_in[8];
  const float* fW1 = (const float*)d_in[9];
  const float* fb1 = (const float*)d_in[10];
  const float* fW2 = (const float*)d_in[11];
  const float* fb2 = (const float*)d_in[12];
  float* out = (float*)d_out;

  const int Nn = N_NODES, E = N_EDGES, G = N_GRAPHS;
  const int* src = ei;
  const int* dst = ei + E;

  // ---- workspace layout (~350 MB): everything ping-pongs A <-> B ----
  // A [N,160]: Xh(96) -> H1(96) -> H2(160) -> OUT3(160, reused per L3 pass)
  // B [N,160]: Z1(96) -> Z2(96) -> Z3(160) -> fc1 [G,1056]
  // Garbage pad cols are harmless: every pad feeds a zero-padded weight row.
  _Float16* A = (_Float16*)d_ws;                          // [N,160]
  _Float16* B = A + (size_t)Nn * 160;                     // [N,160]
  _Float16* GA = B + (size_t)Nn * 160;                    // [G,320] chunk80
  _Float16* W1T   = GA + (size_t)G * 320;                 // [80][96]
  _Float16* W2T   = W1T + 80 * 96;                        // [160][96]
  _Float16* W3T   = W2T + 160 * 96;                       // [320][160] chunk80
  _Float16* fW1T  = W3T + 320 * 160;                      // [1040][320] chunk80
  _Float16* fW2T  = fW1T + (size_t)1040 * 320;            // [160][1056]
  float* dinv     = (float*)(fW2T + (size_t)160 * 1056);  // [N]
  int* rowptr     = (int*)(dinv + Nn);                    // [N+1]
  int* cur        = rowptr + Nn + 1;                      // [N]
  int* ssrc       = cur + Nn;                             // [E]
  int* partials   = ssrc + E;                             // [512]
  int* gstart     = partials + 512;                       // [G+1]
  int4* ell = (int4*)(((uintptr_t)(gstart + G + 1) + 15) & ~(uintptr_t)15);  // [N]

  _Float16* Xh = A;      // [N,96]
  _Float16* Z1 = B;      // [N,96]
  _Float16* H1 = A;      // [N,96]
  _Float16* Z2 = B;      // [N,96]
  _Float16* H2 = A;      // [N,160]
  _Float16* Z3 = B;      // [N,160]
  _Float16* O3 = A;      // [N,160] per L3 pass
  _Float16* fc1 = B;     // [G,1056]

  dim3 blk(256);
  const int gN10 = (int)(((unsigned)Nn * 10u + 255u) / 256u);
  const int gN20 = (int)(((unsigned)Nn * 20u + 255u) / 256u);
  const int gG10 = (int)(((unsigned)G * 10u + 255u) / 256u);
  const dim3 nodeGrid(1, (Nn + 127) / 128);
  const dim3 pairGrid(2, (Nn + 127) / 128);
  const int NB = (Nn + 1023) / 1024;  // 489

  // ---- CSR build + ELL + graph starts ----
  fill_u32<<<(Nn + 255) / 256, blk, 0, stream>>>((unsigned*)cur, 0u, Nn);
  hist_dst<<<(E + 255) / 256, blk, 0, stream>>>(dst, cur, E);
  scanA<<<NB, blk, 0, stream>>>(cur, rowptr, partials, Nn);
  scanB<<<1, 512, 0, stream>>>(partials, NB);
  scanC<<<(Nn + 255) / 256, blk, 0, stream>>>(rowptr, partials, cur, Nn, E);
  dinv_k<<<(Nn + 255) / 256, blk, 0, stream>>>(rowptr, dinv, Nn);
  bucket<<<(E + 255) / 256, blk, 0, stream>>>(src, dst, cur, ssrc, E);
  ell_build<<<(Nn + 255) / 256, blk, 0, stream>>>(rowptr, ssrc, ell, Nn);
  graph_starts<<<(Nn + 256) / 256, blk, 0, stream>>>(batch, gstart, Nn);

  // ---- fp16 transposed weights ----
  wt_conv<0><<<(80 * 96 + 255) / 256, blk, 0, stream>>>(W1, W1T, 78, 78, 78, 96, 80 * 96);
  wt_conv<0><<<(160 * 96 + 255) / 256, blk, 0, stream>>>(W2, W2T, 78, 156, 156, 96, 160 * 96);
  wt_conv<80><<<(320 * 160 + 255) / 256, blk, 0, stream>>>(W3, W3T, 156, 312, 312, 160, 320 * 160);
  wt_conv<80><<<(1040 * 320 + 255) / 256, blk, 0, stream>>>(fW1, fW1T, 312, 1024, 1024, 320, 1040 * 320);
  wt_conv<0><<<(160 * 1056 + 255) / 256, blk, 0, stream>>>(fW2, fW2T, 1024, 128, 128, 1056, 160 * 1056);

  // ---- x -> f16 X' = D X [N,96] ----
  xconv<<<(int)(((unsigned)Nn * 48u + 255u) / 256u), blk, 0, stream>>>(x, dinv, Xh);

  // ---- layer 1: Z1 = D(I+A)X' ; H1 = relu(Z1 W1 + b1) * dinv ----
  aggregateZ<96, 10><<<gN10, blk, 0, stream>>>(Xh, ell, rowptr, ssrc, dinv, Z1, 96);
  gemm_direct<96, 3, 1, 0><<<nodeGrid, blk, 0, stream>>>(Z1, W1T, H1, dinv, b1, Nn, 78, 96, 0);

  // ---- layer 2: Z2 = D(I+A)H1 ; H2 = relu(Z2 W2 + b2) * dinv  (pair-plane) ----
  aggregateZ<96, 10><<<gN10, blk, 0, stream>>>(H1, ell, rowptr, ssrc, dinv, Z2, 96);
  gemm_direct<96, 3, 1, 1><<<pairGrid, blk, 0, stream>>>(Z2, W2T, H2, dinv, b2, Nn, 78, 160, 80);

  // ---- layer 3: Z3 = D(I+A)H2 ; 2 passes: O3 = relu(Z3 W3 + b3) -> pools ----
  aggregateZ<160, 20><<<gN20, blk, 0, stream>>>(H2, ell, rowptr, ssrc, dinv, Z3, 160);
  for (int p = 0; p < 2; ++p) {
    gemm_direct<160, 1, 1, 1><<<pairGrid, blk, 0, stream>>>(
        Z3, W3T + (size_t)(156 * p) * 160, O3, nullptr, b3 + 156 * p, Nn, 78, 160, 80);
    pool_seq<<<gG10, blk, 0, stream>>>(O3, gstart, GA, 0, (2 * p) * 80);
    pool_seq<<<gG10, blk, 0, stream>>>(O3, gstart, GA, 80, (2 * p + 1) * 80);
  }

  // ---- FC1: relu(GA @ fW1 + fb1) -> fc1 f16 (B staged in 50 KB LDS) ----
  {
    dim3 g((1024 + 79) / 80, (G + 127) / 128);  // 13 x 157
    gemm_direct<320, 1, 1, 0><<<g, blk, 0, stream>>>(GA, fW1T, fc1, nullptr, fb1, G, 1024, 1056, 0);
  }
  // ---- FC2: out = fc1 @ fW2 + fb2 (f32) ----
  {
    dim3 g((128 + 79) / 80, (G + 127) / 128);  // 2 x 157
    gemm_direct<1056, 2, 0, 0><<<g, blk, 0, stream>>>(fc1, fW2T, out, nullptr, fb2, G, 128, 128, 0);
  }
}

// Round 15
// 1020.418 us; speedup vs baseline: 1.9872x; 1.0711x over previous
//
#include <hip/hip_runtime.h>
#include <hip/hip_fp16.h>

#define N_NODES 500000
#define N_EDGES 1000000
#define N_GRAPHS 20000

typedef _Float16 f16x8 __attribute__((ext_vector_type(8)));
typedef float f32x4 __attribute__((ext_vector_type(4)));

__global__ __launch_bounds__(256) void fill_u32(unsigned* p, unsigned v, int n) {
  int i = blockIdx.x * 256 + threadIdx.x;
  if (i < n) p[i] = v;
}

__global__ __launch_bounds__(256) void hist_dst(const int* __restrict__ dst, int* cnt, int e) {
  int i = blockIdx.x * 256 + threadIdx.x;
  if (i < e) atomicAdd(&cnt[dst[i]], 1);
}

// ---- 2-level exclusive scan over deg[N] (1024 elems/block) ----
__global__ __launch_bounds__(256) void scanA(const int* __restrict__ deg, int* __restrict__ loc,
                                             int* __restrict__ partials, int n) {
  __shared__ int ts[256];
  int b = blockIdx.x, t = threadIdx.x;
  int base = b * 1024 + t * 4;
  int v[4], s = 0;
#pragma unroll
  for (int j = 0; j < 4; ++j) {
    v[j] = (base + j < n) ? deg[base + j] : 0;
    s += v[j];
  }
  ts[t] = s;
  __syncthreads();
  for (int off = 1; off < 256; off <<= 1) {
    int x = (t >= off) ? ts[t - off] : 0;
    __syncthreads();
    ts[t] += x;
    __syncthreads();
  }
  if (t == 255) partials[b] = ts[255];
  int run = ts[t] - s;  // exclusive
#pragma unroll
  for (int j = 0; j < 4; ++j) {
    if (base + j < n) loc[base + j] = run;
    run += v[j];
  }
}

__global__ __launch_bounds__(512) void scanB(int* partials, int nb) {
  __shared__ int s[512];
  int t = threadIdx.x;
  s[t] = (t < nb) ? partials[t] : 0;
  __syncthreads();
  if (t == 0) {
    int run = 0;
    for (int i = 0; i < nb; ++i) { int v = s[i]; s[i] = run; run += v; }
  }
  __syncthreads();
  if (t < nb) partials[t] = s[t];
}

__global__ __launch_bounds__(256) void scanC(int* __restrict__ rowptr, const int* __restrict__ partials,
                                             int* __restrict__ cur, int n, int e) {
  int i = blockIdx.x * 256 + threadIdx.x;
  if (i < n) {
    int v = rowptr[i] + partials[i >> 10];
    rowptr[i] = v;
    cur[i] = v;
  }
  if (i == 0) rowptr[n] = e;
}

__global__ __launch_bounds__(256) void dinv_k(const int* __restrict__ rowptr, float* dinv, int n) {
  int i = blockIdx.x * 256 + threadIdx.x;
  if (i < n) dinv[i] = rsqrtf(1.0f + (float)(rowptr[i + 1] - rowptr[i]));
}

__global__ __launch_bounds__(256) void bucket(const int* __restrict__ src, const int* __restrict__ dst,
                                              int* __restrict__ cur, int* __restrict__ ssrc, int e) {
  int i = blockIdx.x * 256 + threadIdx.x;
  if (i < e) ssrc[atomicAdd(&cur[dst[i]], 1)] = src[i];
}

// ell[n] = {deg, s0, s1, s2}
__global__ __launch_bounds__(256) void ell_build(const int* __restrict__ rowptr,
                                                 const int* __restrict__ ssrc,
                                                 int4* __restrict__ ell, int n) {
  int i = blockIdx.x * 256 + threadIdx.x;
  if (i >= n) return;
  int r0 = rowptr[i], r1 = rowptr[i + 1];
  int deg = r1 - r0;
  int4 e;
  e.x = deg;
  e.y = (deg > 0) ? ssrc[r0] : 0;
  e.z = (deg > 1) ? ssrc[r0 + 1] : 0;
  e.w = (deg > 2) ? ssrc[r0 + 2] : 0;
  ell[i] = e;
}

// gstart[g] = first node index of graph g (batch sorted); gstart[G] = N
__global__ __launch_bounds__(256) void graph_starts(const int* __restrict__ batch,
                                                    int* __restrict__ gstart, int n) {
  int i = blockIdx.x * 256 + threadIdx.x;
  if (i < n) {
    int b = batch[i];
    int bp = (i == 0) ? -1 : batch[i - 1];
    for (int g = bp + 1; g <= b; ++g) gstart[g] = i;
  } else if (i == n) {
    int bl = batch[n - 1];
    for (int g = bl + 1; g <= N_GRAPHS; ++g) gstart[g] = n;
  }
}

// WT[c][k'] = f16(W[k][c]); CW>0: chunk layout, k = 78*(k'/CW) + k'%CW, valid (k'%CW)<78
template <int CW>
__global__ __launch_bounds__(256) void wt_conv(const float* __restrict__ W, _Float16* __restrict__ WT,
                                               int K, int Nout, int ldw, int KP, int total) {
  int i = blockIdx.x * 256 + threadIdx.x;
  if (i >= total) return;
  int c = i / KP, kp = i - c * KP;
  int k; bool valid;
  if (CW) { int blk = kp / CW, r = kp - blk * CW; k = blk * 78 + r; valid = (r < 78) && (k < K); }
  else { k = kp; valid = kp < K; }
  WT[i] = (valid && c < Nout) ? (_Float16)W[(size_t)k * ldw + c] : (_Float16)0.f;
}

// Xh[n, 0:96] = f16(x[n, 0:78] * dinv[n]), zero pad (pre-scaled activations X' = D X)
__global__ __launch_bounds__(256) void xconv(const float* __restrict__ xin,
                                             const float* __restrict__ dinv,
                                             _Float16* __restrict__ Xh) {
  unsigned idx = blockIdx.x * 256u + threadIdx.x;
  if (idx >= (unsigned)N_NODES * 48u) return;
  unsigned n = idx / 48u, c2 = idx - n * 48u;
  __half2 h = __floats2half2_rn(0.f, 0.f);
  if (c2 < 39u) {
    float di = dinv[n];
    float2 v = *reinterpret_cast<const float2*>(xin + (size_t)n * 78 + 2 * c2);
    h = __floats2half2_rn(v.x * di, v.y * di);
  }
  *reinterpret_cast<__half2*>((__half*)Xh + (size_t)n * 96 + 2 * c2) = h;
}

// Direct-register MFMA GEMM. in [M,KP] f16; WT [*,KP] f16 pre-transposed. Tile 128x80.
// BLDS=1: stage B in LDS fragment-linear (conflict-free), single barrier.
// PLANE=1: blockIdx.x = output chunk; out16 += x*planeStride, WT += x*78*KP, bias += x*78.
// NS<=5: A-fragments hoisted to regs and PINNED with sched_barrier(0) so all 2*NS
//        HBM loads stay in flight (r14 showed compiler sinks them: VGPR=52).
// TSTORE (BLDS && f16 out): stage output tile in reused Bs LDS, then coalesced
//        uint4 stores (1280/block) instead of 10240 scalar 2B stores.
// OUT_MODE 1: relu(v+b) -> f16 ; 2: v+b -> f32 ; 3: relu(v+b)*rs[row] -> f16
template <int KP, int OUT_MODE, int BLDS, int PLANE>
__global__ __launch_bounds__(256) void gemm_direct(
    const _Float16* __restrict__ in, const _Float16* __restrict__ WT,
    void* __restrict__ outp, const float* __restrict__ rs, const float* __restrict__ bo,
    int M, int Nout, int LDO, size_t planeStride) {
  constexpr int NS = KP / 32;
  constexpr bool HOIST = (NS <= 5);
  constexpr bool TSTORE = (BLDS != 0) && (OUT_MODE != 2);
  constexpr int BS_BYTES = BLDS ? 5 * NS * 64 * 16 : 16;
  constexpr int SM_BYTES = TSTORE ? (BS_BYTES > 20480 ? BS_BYTES : 20480) : BS_BYTES;
  __shared__ __align__(16) char smem[SM_BYTES];
  _Float16* Bs = (_Float16*)smem;
  const int tid = threadIdx.x;
  const int lane = tid & 63;
  const int wid = tid >> 6;
  const int row0 = blockIdx.y * 128;
  const int col0 = PLANE ? 0 : blockIdx.x * 80;
  const _Float16* wt = WT + (size_t)(PLANE ? blockIdx.x * 78 : col0) * KP;
  const float* bop = PLANE ? bo + blockIdx.x * 78 : bo;
  _Float16* out16 = (_Float16*)outp + (PLANE ? (size_t)blockIdx.x * planeStride : 0);
  float* out32 = (float*)outp;
  const int koff = (lane >> 4) * 8;
  const int gr0 = row0 + wid * 32 + (lane & 15);
  const bool v0 = gr0 < M, v1 = (gr0 + 16) < M;
  const _Float16* a0 = in + (size_t)gr0 * KP + koff;
  const _Float16* a1 = a0 + (size_t)16 * KP;
  const _Float16* bp = wt + (size_t)(lane & 15) * KP + koff;

  const f16x8 zf = {0, 0, 0, 0, 0, 0, 0, 0};
  const f32x4 z4 = {0.f, 0.f, 0.f, 0.f};

  // ---- issue ALL A-loads first (overlap B-staging + barrier), pin with sched_barrier ----
  f16x8 A0[HOIST ? NS : 1], A1[HOIST ? NS : 1];
  if constexpr (HOIST) {
#pragma unroll
    for (int s = 0; s < NS; ++s) {
      A0[s] = v0 ? *reinterpret_cast<const f16x8*>(a0 + s * 32) : zf;
      A1[s] = v1 ? *reinterpret_cast<const f16x8*>(a1 + s * 32) : zf;
    }
    __builtin_amdgcn_sched_barrier(0);
  }

  if (BLDS) {
    for (int i = tid; i < 5 * NS * 64; i += 256) {
      int l = i & 63;
      int nf = (i >> 6) % 5;
      int s = i / 320;
      int r = nf * 16 + (l & 15);
      int k = s * 32 + ((l >> 4) << 3);
      *reinterpret_cast<uint4*>(&Bs[(size_t)i * 8]) =
          *reinterpret_cast<const uint4*>(wt + (size_t)r * KP + k);
    }
    __syncthreads();
  }

  f32x4 acc[2][5];
#pragma unroll
  for (int a = 0; a < 2; ++a)
#pragma unroll
    for (int b = 0; b < 5; ++b) acc[a][b] = z4;

  if constexpr (HOIST) {
#pragma unroll
    for (int s = 0; s < NS; ++s) {
      f16x8 bf[5];
#pragma unroll
      for (int nf = 0; nf < 5; ++nf) {
        if (BLDS)
          bf[nf] = *reinterpret_cast<const f16x8*>(&Bs[((size_t)(s * 5 + nf) * 64 + lane) * 8]);
        else
          bf[nf] = *reinterpret_cast<const f16x8*>(bp + (size_t)nf * 16 * KP + s * 32);
      }
#pragma unroll
      for (int nf = 0; nf < 5; ++nf) {
        acc[0][nf] = __builtin_amdgcn_mfma_f32_16x16x32_f16(A0[s], bf[nf], acc[0][nf], 0, 0, 0);
        acc[1][nf] = __builtin_amdgcn_mfma_f32_16x16x32_f16(A1[s], bf[nf], acc[1][nf], 0, 0, 0);
      }
    }
  } else {
#pragma unroll
    for (int s = 0; s < NS; ++s) {
      f16x8 af0 = v0 ? *reinterpret_cast<const f16x8*>(a0 + s * 32) : zf;
      f16x8 af1 = v1 ? *reinterpret_cast<const f16x8*>(a1 + s * 32) : zf;
      f16x8 bf[5];
#pragma unroll
      for (int nf = 0; nf < 5; ++nf) {
        if (BLDS)
          bf[nf] = *reinterpret_cast<const f16x8*>(&Bs[((size_t)(s * 5 + nf) * 64 + lane) * 8]);
        else
          bf[nf] = *reinterpret_cast<const f16x8*>(bp + (size_t)nf * 16 * KP + s * 32);
      }
#pragma unroll
      for (int nf = 0; nf < 5; ++nf) {
        acc[0][nf] = __builtin_amdgcn_mfma_f32_16x16x32_f16(af0, bf[nf], acc[0][nf], 0, 0, 0);
        acc[1][nf] = __builtin_amdgcn_mfma_f32_16x16x32_f16(af1, bf[nf], acc[1][nf], 0, 0, 0);
      }
    }
  }

  if constexpr (TSTORE) {
    // ---- transposed store: acc -> LDS f16 tile [128][80] -> coalesced uint4 ----
    __syncthreads();  // all waves done reading Bs
    _Float16* Os = (_Float16*)smem;
#pragma unroll
    for (int rf = 0; rf < 2; ++rf) {
#pragma unroll
      for (int j = 0; j < 4; ++j) {
        int rl = wid * 32 + rf * 16 + (lane >> 4) * 4 + j;
        int gr = row0 + rl;
        float sc = (OUT_MODE == 3 && gr < M) ? rs[gr] : 0.f;
#pragma unroll
        for (int nf = 0; nf < 5; ++nf) {
          int cl = nf * 16 + (lane & 15);
          int oc = col0 + cl;
          float r = 0.f;
          if (oc < Nout) {
            r = fmaxf(acc[rf][nf][j] + bop[oc], 0.f);
            if (OUT_MODE == 3) r *= sc;
          }
          Os[rl * 80 + cl] = (_Float16)r;
        }
      }
    }
    __syncthreads();
    for (int i = tid; i < 1280; i += 256) {
      int rl = i / 10, u = i - rl * 10;
      int gr = row0 + rl;
      if (gr < M)
        *reinterpret_cast<uint4*>(&out16[(size_t)gr * LDO + col0 + u * 8]) =
            *reinterpret_cast<const uint4*>(&Os[rl * 80 + u * 8]);
    }
  } else {
    // epilogue: C/D col=lane&15, row=(lane>>4)*4+reg
#pragma unroll
    for (int rf = 0; rf < 2; ++rf) {
#pragma unroll
      for (int j = 0; j < 4; ++j) {
        int gr = row0 + wid * 32 + rf * 16 + (lane >> 4) * 4 + j;
        if (gr >= M) continue;
        float sc = (OUT_MODE == 3) ? rs[gr] : 0.f;
#pragma unroll
        for (int nf = 0; nf < 5; ++nf) {
          int oc = col0 + nf * 16 + (lane & 15);
          if (oc >= Nout) continue;
          float v = acc[rf][nf][j];
          if (OUT_MODE == 1) {
            out16[(size_t)gr * LDO + oc] = (_Float16)fmaxf(v + bop[oc], 0.f);
          } else if (OUT_MODE == 3) {
            out16[(size_t)gr * LDO + oc] = (_Float16)(fmaxf(v + bop[oc], 0.f) * sc);
          } else {
            out32[(size_t)gr * LDO + oc] = v + bop[oc];
          }
        }
      }
    }
  }
}

__device__ inline void acc8(float* a, uint4 v) {
  const __half2* h = reinterpret_cast<const __half2*>(&v);
#pragma unroll
  for (int j = 0; j < 4; ++j) {
    float2 f = __half22float2(h[j]);
    a[2 * j] += f.x;
    a[2 * j + 1] += f.y;
  }
}

// segment-sum gather; hs rows have stride LDI f16 from hbase
template <int LDI>
__device__ inline void gather_sumT(float* a, const _Float16* hbase, unsigned n,
                                   const int4* __restrict__ ell,
                                   const int* __restrict__ rowptr,
                                   const int* __restrict__ ssrc) {
  int4 e = ell[n];
  const int deg = e.x;
  uint4 sv = *reinterpret_cast<const uint4*>(hbase + (size_t)n * LDI);
  uint4 g0, g1, g2;
  if (deg > 0) g0 = *reinterpret_cast<const uint4*>(hbase + (size_t)e.y * LDI);
  if (deg > 1) g1 = *reinterpret_cast<const uint4*>(hbase + (size_t)e.z * LDI);
  if (deg > 2) g2 = *reinterpret_cast<const uint4*>(hbase + (size_t)e.w * LDI);
  {
    const __half2* h = reinterpret_cast<const __half2*>(&sv);
#pragma unroll
    for (int j = 0; j < 4; ++j) {
      float2 f = __half22float2(h[j]);
      a[2 * j] = f.x;
      a[2 * j + 1] = f.y;
    }
  }
  if (deg > 0) acc8(a, g0);
  if (deg > 1) acc8(a, g1);
  if (deg > 2) acc8(a, g2);
  if (deg > 3) {
    int r = rowptr[n] + 3, r1 = r + deg - 3;
    for (; r + 2 <= r1; r += 2) {
      uint4 va = *reinterpret_cast<const uint4*>(hbase + (size_t)ssrc[r] * LDI);
      uint4 vb = *reinterpret_cast<const uint4*>(hbase + (size_t)ssrc[r + 1] * LDI);
      acc8(a, va);
      acc8(a, vb);
    }
    if (r < r1) {
      uint4 va = *reinterpret_cast<const uint4*>(hbase + (size_t)ssrc[r] * LDI);
      acc8(a, va);
    }
  }
}

// Input-side aggregation: Z[n] = f16(dinv[n] * (in[n] + Σ_seg in[ssrc]))
template <int LDI, int NSUB>
__global__ __launch_bounds__(256) void aggregateZ(
    const _Float16* __restrict__ in, const int4* __restrict__ ell,
    const int* __restrict__ rowptr, const int* __restrict__ ssrc,
    const float* __restrict__ dinv, _Float16* __restrict__ outZ, int ldo) {
  unsigned idx = blockIdx.x * 256u + threadIdx.x;
  if (idx >= (unsigned)N_NODES * NSUB) return;
  unsigned n = idx / NSUB, sub = idx - n * NSUB;
  float a[8];
  gather_sumT<LDI>(a, in + sub * 8u, n, ell, rowptr, ssrc);
  float di = dinv[n];
  _Float16 ov[8];
#pragma unroll
  for (int j = 0; j < 8; ++j) ov[j] = (_Float16)(di * a[j]);
  *reinterpret_cast<uint4*>(outZ + (size_t)n * ldo + sub * 8u) =
      *reinterpret_cast<const uint4*>(ov);
}

// Mean-pool over contiguous node range, 16B/thread (10 threads/graph):
// GA[g*320 + coffGA + q*8..] = (1/cnt) Σ_n in[n*160 + inOff + q*8..]
__global__ __launch_bounds__(256) void pool_seq(
    const _Float16* __restrict__ in, const int* __restrict__ gstart,
    _Float16* __restrict__ GA, int inOff, int coffGA) {
  unsigned idx = blockIdx.x * 256u + threadIdx.x;
  if (idx >= (unsigned)N_GRAPHS * 10u) return;
  unsigned g = idx / 10u, q = idx - g * 10u;
  int n0 = gstart[g], n1 = gstart[g + 1];
  const _Float16* base = in + inOff + q * 8;
  float a[8] = {0.f, 0.f, 0.f, 0.f, 0.f, 0.f, 0.f, 0.f};
  float b2[8] = {0.f, 0.f, 0.f, 0.f, 0.f, 0.f, 0.f, 0.f};
  int n = n0;
  for (; n + 2 <= n1; n += 2) {
    uint4 va = *reinterpret_cast<const uint4*>(base + (size_t)n * 160);
    uint4 vb = *reinterpret_cast<const uint4*>(base + (size_t)(n + 1) * 160);
    acc8(a, va);
    acc8(b2, vb);
  }
  if (n < n1) {
    uint4 va = *reinterpret_cast<const uint4*>(base + (size_t)n * 160);
    acc8(a, va);
  }
  float gi = 1.0f / fmaxf((float)(n1 - n0), 1.0f);
  _Float16 ov[8];
#pragma unroll
  for (int j = 0; j < 8; ++j) ov[j] = (_Float16)((a[j] + b2[j]) * gi);
  *reinterpret_cast<uint4*>(GA + (size_t)g * 320 + coffGA + q * 8) =
      *reinterpret_cast<const uint4*>(ov);
}

extern "C" void kernel_launch(void* const* d_in, const int* in_sizes, int n_in,
                              void* d_out, int out_size, void* d_ws, size_t ws_size,
                              hipStream_t stream) {
  const float* x   = (const float*)d_in[0];
  const int* ei    = (const int*)d_in[1];
  const int* batch = (const int*)d_in[2];
  const float* W1 = (const float*)d_in[3];
  const float* b1 = (const float*)d_in[4];
  const float* W2 = (const float*)d_in[5];
  const float* b2 = (const float*)d_in[6];
  const float* W3 = (const float*)d_in[7];
  const float* b3 = (const float*)d_in[8];
  const float* fW1 = (const float*)d_in[9];
  const float* fb1 = (const float*)d_in[10];
  const float* fW2 = (const float*)d_in[11];
  const float* fb2 = (const float*)d_in[12];
  float* out = (float*)d_out;

  const int Nn = N_NODES, E = N_EDGES, G = N_GRAPHS;
  const int* src = ei;
  const int* dst = ei + E;

  // ---- workspace layout (~350 MB): ping-pong A <-> B ----
  _Float16* A = (_Float16*)d_ws;                          // [N,160]
  _Float16* B = A + (size_t)Nn * 160;                     // [N,160]
  _Float16* GA = B + (size_t)Nn * 160;                    // [G,320] chunk80
  _Float16* W1T   = GA + (size_t)G * 320;                 // [80][96]
  _Float16* W2T   = W1T + 80 * 96;                        // [160][96]
  _Float16* W3T   = W2T + 160 * 96;                       // [320][160] chunk80
  _Float16* fW1T  = W3T + 320 * 160;                      // [1040][320] chunk80
  _Float16* fW2T  = fW1T + (size_t)1040 * 320;            // [160][1056]
  float* dinv     = (float*)(fW2T + (size_t)160 * 1056);  // [N]
  int* rowptr     = (int*)(dinv + Nn);                    // [N+1]
  int* cur        = rowptr + Nn + 1;                      // [N]
  int* ssrc       = cur + Nn;                             // [E]
  int* partials   = ssrc + E;                             // [512]
  int* gstart     = partials + 512;                       // [G+1]
  int4* ell = (int4*)(((uintptr_t)(gstart + G + 1) + 15) & ~(uintptr_t)15);  // [N]

  _Float16* Xh = A;      // [N,96]
  _Float16* Z1 = B;      // [N,96]
  _Float16* H1 = A;      // [N,96]
  _Float16* Z2 = B;      // [N,96]
  _Float16* H2 = A;      // [N,160]
  _Float16* Z3 = B;      // [N,160]
  _Float16* O3 = A;      // [N,160] per L3 pass
  _Float16* fc1 = B;     // [G,1056]

  dim3 blk(256);
  const int gN10 = (int)(((unsigned)Nn * 10u + 255u) / 256u);
  const int gN20 = (int)(((unsigned)Nn * 20u + 255u) / 256u);
  const int gG10 = (int)(((unsigned)G * 10u + 255u) / 256u);
  const dim3 nodeGrid(1, (Nn + 127) / 128);
  const dim3 pairGrid(2, (Nn + 127) / 128);
  const int NB = (Nn + 1023) / 1024;  // 489

  // ---- CSR build + ELL + graph starts ----
  fill_u32<<<(Nn + 255) / 256, blk, 0, stream>>>((unsigned*)cur, 0u, Nn);
  hist_dst<<<(E + 255) / 256, blk, 0, stream>>>(dst, cur, E);
  scanA<<<NB, blk, 0, stream>>>(cur, rowptr, partials, Nn);
  scanB<<<1, 512, 0, stream>>>(partials, NB);
  scanC<<<(Nn + 255) / 256, blk, 0, stream>>>(rowptr, partials, cur, Nn, E);
  dinv_k<<<(Nn + 255) / 256, blk, 0, stream>>>(rowptr, dinv, Nn);
  bucket<<<(E + 255) / 256, blk, 0, stream>>>(src, dst, cur, ssrc, E);
  ell_build<<<(Nn + 255) / 256, blk, 0, stream>>>(rowptr, ssrc, ell, Nn);
  graph_starts<<<(Nn + 256) / 256, blk, 0, stream>>>(batch, gstart, Nn);

  // ---- fp16 transposed weights ----
  wt_conv<0><<<(80 * 96 + 255) / 256, blk, 0, stream>>>(W1, W1T, 78, 78, 78, 96, 80 * 96);
  wt_conv<0><<<(160 * 96 + 255) / 256, blk, 0, stream>>>(W2, W2T, 78, 156, 156, 96, 160 * 96);
  wt_conv<80><<<(320 * 160 + 255) / 256, blk, 0, stream>>>(W3, W3T, 156, 312, 312, 160, 320 * 160);
  wt_conv<80><<<(1040 * 320 + 255) / 256, blk, 0, stream>>>(fW1, fW1T, 312, 1024, 1024, 320, 1040 * 320);
  wt_conv<0><<<(160 * 1056 + 255) / 256, blk, 0, stream>>>(fW2, fW2T, 1024, 128, 128, 1056, 160 * 1056);

  // ---- x -> f16 X' = D X [N,96] ----
  xconv<<<(int)(((unsigned)Nn * 48u + 255u) / 256u), blk, 0, stream>>>(x, dinv, Xh);

  // ---- layer 1: Z1 = D(I+A)X' ; H1 = relu(Z1 W1 + b1) * dinv ----
  aggregateZ<96, 10><<<gN10, blk, 0, stream>>>(Xh, ell, rowptr, ssrc, dinv, Z1, 96);
  gemm_direct<96, 3, 1, 0><<<nodeGrid, blk, 0, stream>>>(Z1, W1T, H1, dinv, b1, Nn, 78, 96, 0);

  // ---- layer 2: Z2 = D(I+A)H1 ; H2 = relu(Z2 W2 + b2) * dinv  (pair-plane) ----
  aggregateZ<96, 10><<<gN10, blk, 0, stream>>>(H1, ell, rowptr, ssrc, dinv, Z2, 96);
  gemm_direct<96, 3, 1, 1><<<pairGrid, blk, 0, stream>>>(Z2, W2T, H2, dinv, b2, Nn, 78, 160, 80);

  // ---- layer 3: Z3 = D(I+A)H2 ; 2 passes: O3 = relu(Z3 W3 + b3) -> pools ----
  aggregateZ<160, 20><<<gN20, blk, 0, stream>>>(H2, ell, rowptr, ssrc, dinv, Z3, 160);
  for (int p = 0; p < 2; ++p) {
    gemm_direct<160, 1, 1, 1><<<pairGrid, blk, 0, stream>>>(
        Z3, W3T + (size_t)(156 * p) * 160, O3, nullptr, b3 + 156 * p, Nn, 78, 160, 80);
    pool_seq<<<gG10, blk, 0, stream>>>(O3, gstart, GA, 0, (2 * p) * 80);
    pool_seq<<<gG10, blk, 0, stream>>>(O3, gstart, GA, 80, (2 * p + 1) * 80);
  }

  // ---- FC1: relu(GA @ fW1 + fb1) -> fc1 f16 (B staged in 50 KB LDS) ----
  {
    dim3 g((1024 + 79) / 80, (G + 127) / 128);  // 13 x 157
    gemm_direct<320, 1, 1, 0><<<g, blk, 0, stream>>>(GA, fW1T, fc1, nullptr, fb1, G, 1024, 1056, 0);
  }
  // ---- FC2: out = fc1 @ fW2 + fb2 (f32) ----
  {
    dim3 g((128 + 79) / 80, (G + 127) / 128);  // 2 x 157
    gemm_direct<1056, 2, 0, 0><<<g, blk, 0, stream>>>(fc1, fW2T, out, nullptr, fb2, G, 128, 128, 0);
  }
}